// Round 5
// baseline (9494.467 us; speedup 1.0000x reference)
//
#include <hip/hip_runtime.h>
#include <hip/hip_bf16.h>
#include <hip/hip_cooperative_groups.h>

namespace cg = cooperative_groups;

// Sizes
#define U_    1200
#define E_    620
#define B_    128
#define T_    64
#define N3    3600           // 3*U
#define NP    3712           // padded 3U = 29*128
#define KE    640            // padded E  = 10*64
#define KU    1216           // padded U  = 19*64
#define WIN   16             // xproj window (scan steps per window GEMM)
#define NBLK  232            // persistent blocks: 2 dirs x 58 ntile64 x 2 khalf
#define LN_EPS 1e-3f

typedef __attribute__((ext_vector_type(8))) short short8;
typedef __attribute__((ext_vector_type(4))) float f32x4;

// ---------------- workspace layout (bytes) ----------------
constexpr size_t OFF_EMBH  = 0;                                   // bf16 [8192][KE] hi
constexpr size_t SZ_EMB    = (size_t)8192 * KE * 2;
constexpr size_t OFF_EMBL  = OFF_EMBH + SZ_EMB;
constexpr size_t OFF_KTH   = OFF_EMBL + SZ_EMB;                   // bf16 [2][NP][KE] hi
constexpr size_t SZ_KT     = (size_t)2 * NP * KE * 2;
constexpr size_t OFF_KTL   = OFF_KTH + SZ_KT;
constexpr size_t OFF_RKTH  = OFF_KTL + SZ_KT;                     // bf16 [2][NP][KU] hi
constexpr size_t SZ_RKT    = (size_t)2 * NP * KU * 2;
constexpr size_t OFF_RKTL  = OFF_RKTH + SZ_RKT;
constexpr size_t OFF_XPWH  = OFF_RKTL + SZ_RKT;                   // bf16 [2][WIN][B][NP] hi
constexpr size_t SZ_XPW    = (size_t)2 * WIN * B_ * NP * 2;
constexpr size_t OFF_XPWL  = OFF_XPWH + SZ_XPW;
constexpr size_t OFF_INNER = OFF_XPWL + SZ_XPW;                   // f32 [2dirs*2kp][B][NP]
constexpr size_t SZ_INNER  = (size_t)4 * B_ * NP * 4;
constexpr size_t OFF_HLN   = OFF_INNER + SZ_INNER;                // f32 [2][B][U]
constexpr size_t SZ_HLN    = (size_t)2 * B_ * U_ * 4;
constexpr size_t OFF_HLNBH = OFF_HLN + SZ_HLN;                    // bf16 [2][B][KU] hi
constexpr size_t SZ_HLNB   = (size_t)2 * B_ * KU * 2;
constexpr size_t OFF_HLNBL = OFF_HLNBH + SZ_HLNB;

__device__ inline void lds_load16(const void* g, void* l) {
  __builtin_amdgcn_global_load_lds(
      (const __attribute__((address_space(1))) unsigned int*)g,
      (__attribute__((address_space(3))) unsigned int*)l, 16, 0, 0);
}

__device__ inline float sigmf(float x) { return 1.f / (1.f + expf(-x)); }

// ---------------- K1: embedding gather + tanh (fp32 out + hi/lo bf16) -----
__global__ __launch_bounds__(256)
void embed_kernel(const int* __restrict__ sent, const float* __restrict__ embed,
                  float* __restrict__ out_emb,
                  __hip_bfloat16* __restrict__ embH, __hip_bfloat16* __restrict__ embL) {
  const int row = blockIdx.x;                 // b*T + t
  const int idx = sent[row];
  const float* src = embed + (size_t)idx * E_;
  for (int e = threadIdx.x; e < KE; e += 256) {
    float v = 0.f;
    if (e < E_) {
      v = tanhf(src[e]);
      out_emb[(size_t)row * E_ + e] = v;
    }
    const __hip_bfloat16 hi = __float2bfloat16(v);
    embH[(size_t)row * KE + e] = hi;
    embL[(size_t)row * KE + e] = __float2bfloat16(v - __bfloat162float(hi));
  }
}

// ---------------- K2: transpose+cast [K][3600]f32 -> [NP][Kp] hi/lo bf16 ---
__global__ __launch_bounds__(256)
void transpose_cast(const float* __restrict__ W0, const float* __restrict__ W1,
                    __hip_bfloat16* __restrict__ WtHi, __hip_bfloat16* __restrict__ WtLo,
                    int Kreal, int Kp) {
  const int d = blockIdx.z;
  const float* W = d ? W1 : W0;
  __hip_bfloat16* dstH = WtHi + (size_t)d * NP * Kp;
  __hip_bfloat16* dstL = WtLo + (size_t)d * NP * Kp;
  __shared__ float tile[32][33];
  const int n0 = blockIdx.x * 32, k0 = blockIdx.y * 32;
  const int tx = threadIdx.x, ty = threadIdx.y;   // 32 x 8
#pragma unroll
  for (int i = 0; i < 32; i += 8) {
    const int k = k0 + ty + i, n = n0 + tx;
    tile[ty + i][tx] = (k < Kreal && n < N3) ? W[(size_t)k * N3 + n] : 0.f;
  }
  __syncthreads();
#pragma unroll
  for (int i = 0; i < 32; i += 8) {
    const int n = n0 + ty + i, k = k0 + tx;
    const float v = tile[tx][ty + i];
    const __hip_bfloat16 hi = __float2bfloat16(v);
    dstH[(size_t)n * Kp + k] = hi;
    dstL[(size_t)n * Kp + k] = __float2bfloat16(v - __bfloat162float(hi));
  }
}

// ---------------- K4: init h_ln = LN(0) = beta ----------------
__global__ __launch_bounds__(256)
void init_hln(const float* __restrict__ fw_b0, const float* __restrict__ bw_b0,
              float* __restrict__ hln, __hip_bfloat16* __restrict__ hlnbH,
              __hip_bfloat16* __restrict__ hlnbL) {
  const int idx = blockIdx.x * 256 + threadIdx.x;   // [2*128*KU]
  if (idx >= 2 * B_ * KU) return;
  const int k = idx % KU;
  const int rowd = idx / KU;
  const int d = rowd >> 7;
  float v = 0.f;
  if (k < U_) {
    v = (d ? bw_b0 : fw_b0)[k];
    hln[(size_t)rowd * U_ + k] = v;
  }
  const __hip_bfloat16 hi = __float2bfloat16(v);
  hlnbH[idx] = hi;
  hlnbL[idx] = __float2bfloat16(v - __bfloat162float(hi));
}

// ---------------- window GEMM: x+ib for WIN scan steps, hi/lo out ---------
__global__ __launch_bounds__(256)
void xwin_gemm(const __hip_bfloat16* __restrict__ embH, const __hip_bfloat16* __restrict__ embL,
               const __hip_bfloat16* __restrict__ kTH, const __hip_bfloat16* __restrict__ kTL,
               const float* __restrict__ fw_bias, const float* __restrict__ bw_bias,
               __hip_bfloat16* __restrict__ xpwH, __hip_bfloat16* __restrict__ xpwL,
               int w0) {
  constexpr int BM = 128, BN = 128, BK = 64;
  constexpr int WM = 64, WN = 64, FM = 4, FN = 4;
  constexpr int TA = BM * BK, TB = BN * BK;       // 8192 elems
  const int d = blockIdx.z;
  const __hip_bfloat16* BH = kTH + (size_t)d * NP * KE;
  const __hip_bfloat16* BL = kTL + (size_t)d * NP * KE;

  const int m0 = blockIdx.y * BM;
  const int n0 = blockIdx.x * BN;
  const int tid = threadIdx.x;
  const int lane = tid & 63;
  const int wid = tid >> 6;
  const int wr = wid >> 1, wc = wid & 1;

  __shared__ __align__(16) __hip_bfloat16 As[2 * TA];
  __shared__ __align__(16) __hip_bfloat16 Bs[2 * TB];

  f32x4 acc[FM][FN] = {};

  const int srow = tid >> 3;
  const int scol = (tid & 7) << 3;

  for (int ks = 0; ks < KE / BK; ++ks) {
    const int k0 = ks * BK;
    __syncthreads();
#pragma unroll
    for (int it = 0; it < TA / 2048; ++it) {
      const int row = m0 + it * 32 + srow;       // m index
      const int b = row & 127, srel = row >> 7;
      const int txi = d ? (T_ - 1 - (w0 + srel)) : (w0 + srel);
      const size_t goff = (size_t)(b * T_ + txi) * KE + k0 + scol;
      lds_load16(embH + goff, As + it * 2048 + tid * 8);
      lds_load16(embL + goff, As + TA + it * 2048 + tid * 8);
    }
#pragma unroll
    for (int it = 0; it < TB / 2048; ++it) {
      const size_t goff = (size_t)(n0 + it * 32 + srow) * KE + k0 + scol;
      lds_load16(BH + goff, Bs + it * 2048 + tid * 8);
      lds_load16(BL + goff, Bs + TB + it * 2048 + tid * 8);
    }
    __syncthreads();
#pragma unroll
    for (int kk = 0; kk < BK / 32; ++kk) {
      short8 ah[FM], al[FM], bh[FN], bl[FN];
#pragma unroll
      for (int mi = 0; mi < FM; ++mi) {
        const int off = (wr * WM + mi * 16 + (lane & 15)) * BK + kk * 32 + (lane >> 4) * 8;
        ah[mi] = *(const short8*)(As + off);
        al[mi] = *(const short8*)(As + TA + off);
      }
#pragma unroll
      for (int ni = 0; ni < FN; ++ni) {
        const int off = (wc * WN + ni * 16 + (lane & 15)) * BK + kk * 32 + (lane >> 4) * 8;
        bh[ni] = *(const short8*)(Bs + off);
        bl[ni] = *(const short8*)(Bs + TB + off);
      }
#pragma unroll
      for (int mi = 0; mi < FM; ++mi)
#pragma unroll
        for (int ni = 0; ni < FN; ++ni) {
          acc[mi][ni] = __builtin_amdgcn_mfma_f32_16x16x32_bf16(ah[mi], bh[ni], acc[mi][ni], 0, 0, 0);
          acc[mi][ni] = __builtin_amdgcn_mfma_f32_16x16x32_bf16(ah[mi], bl[ni], acc[mi][ni], 0, 0, 0);
          acc[mi][ni] = __builtin_amdgcn_mfma_f32_16x16x32_bf16(al[mi], bh[ni], acc[mi][ni], 0, 0, 0);
        }
    }
  }

  const float* ib = d ? bw_bias : fw_bias;
#pragma unroll
  for (int mi = 0; mi < FM; ++mi)
#pragma unroll
    for (int ni = 0; ni < FN; ++ni) {
      const int gc = n0 + wc * WN + ni * 16 + (lane & 15);
      const float bv = (gc < N3) ? ib[gc] : 0.f;
      const int gr0 = m0 + wr * WM + mi * 16 + ((lane >> 4) << 2);
#pragma unroll
      for (int j = 0; j < 4; ++j) {
        const int gr = gr0 + j;
        const int b = gr & 127, srel = gr >> 7;
        const size_t off = ((size_t)(d * WIN + srel) * B_ + b) * NP + gc;
        const float v = acc[mi][ni][j] + bv;
        const __hip_bfloat16 hi = __float2bfloat16(v);
        xpwH[off] = hi;
        xpwL[off] = __float2bfloat16(v - __bfloat162float(hi));
      }
    }
}

// ---------------- block-wide 2-value sum reduction ----------------
__device__ inline void breduce2(float& a, float& b, float* red, int tid) {
#pragma unroll
  for (int off = 32; off; off >>= 1) {
    a += __shfl_down(a, off, 64);
    b += __shfl_down(b, off, 64);
  }
  const int w = tid >> 6;
  __syncthreads();
  if ((tid & 63) == 0) { red[w] = a; red[4 + w] = b; }
  __syncthreads();
  a = red[0] + red[1] + red[2] + red[3];
  b = red[4] + red[5] + red[6] + red[7];
}

// ---------------- persistent cooperative scan kernel ----------------------
// 232 blocks, 1/CU. Block = (dir d, ncol-tile64 nt, K-half kp).
// Weights (hi+lo bf16) LDS-stationary in fragment-contiguous layout:
//   wlds[plane(2)][kk(19)][nf(4)][lane(64)][8elem]  = 155,648 B.
// Per step: GEMM (A-frags direct from global hlnb) -> grid.sync ->
//           fused GRU update (1 row per block; blocks 0..23 take 2) -> sync.
__global__ __launch_bounds__(256)
void scan_persist(const __hip_bfloat16* __restrict__ rkTH, const __hip_bfloat16* __restrict__ rkTL,
                  __hip_bfloat16* __restrict__ hlnbH, __hip_bfloat16* __restrict__ hlnbL,
                  float* __restrict__ hln, float* __restrict__ inner,
                  const __hip_bfloat16* __restrict__ xpwH, const __hip_bfloat16* __restrict__ xpwL,
                  const float* __restrict__ fw_bias, const float* __restrict__ bw_bias,
                  const float* __restrict__ fw_ln0g, const float* __restrict__ fw_ln0b,
                  const float* __restrict__ fw_ln3g, const float* __restrict__ fw_ln3b,
                  const float* __restrict__ bw_ln0g, const float* __restrict__ bw_ln0b,
                  const float* __restrict__ bw_ln3g, const float* __restrict__ bw_ln3b,
                  float* __restrict__ out_tv, int w0) {
  cg::grid_group grid = cg::this_grid();
  __shared__ __hip_bfloat16 wlds[2 * 19 * 4 * 64 * 8];   // 155,648 B
  __shared__ float red[8];

  const int bid = blockIdx.x;
  const int tid = threadIdx.x;
  const int lane = tid & 63;
  const int wid = tid >> 6;

  const int d  = bid / 116;          // direction
  const int rem = bid % 116;
  const int nt = rem >> 1;           // 0..57 (64-col tile)
  const int kp = rem & 1;            // K half
  const int n0 = nt * 64;
  const int kbase = kp * 608;        // 608 = 19*32

  // ---- fill weight LDS (once per launch; amortized over WIN steps) ----
  {
    const __hip_bfloat16* WH = rkTH + (size_t)d * NP * KU;
    const __hip_bfloat16* WL = rkTL + (size_t)d * NP * KU;
    for (int ch = tid; ch < 64 * 76; ch += 256) {   // 76 = 608/8 chunks per row
      const int n = ch / 76, k8 = ch % 76;
      const int kk = k8 >> 2;
      const int l  = ((k8 & 3) << 4) | (n & 15);
      const int nf = n >> 4;
      const size_t g = (size_t)(n0 + n) * KU + kbase + k8 * 8;
      const size_t lo = ((size_t)(kk * 4 + nf) * 64 + l) * 8;
      *(short8*)(wlds + lo)                 = *(const short8*)(WH + g);
      *(short8*)(wlds + 19 * 4 * 512 + lo)  = *(const short8*)(WL + g);
    }
    __syncthreads();
  }

  // A-fragment global offsets (rows = wave's 32 batch rows)
  const int mbase = wid * 32;
  const size_t aoff0 = (size_t)(d * B_ + mbase + (lane & 15)) * KU + kbase + ((lane >> 4) * 8);
  const size_t aoff1 = aoff0 + (size_t)16 * KU;

  for (int s = 0; s < WIN; ++s) {
    // ---------- GEMM phase: inner[(d*2+kp)][128][n0..n0+63] ----------
    f32x4 acc[2][4] = {};
#pragma unroll 1
    for (int kk = 0; kk < 19; ++kk) {
      const size_t ka = (size_t)kk * 32;
      const short8 ah0 = *(const short8*)(hlnbH + aoff0 + ka);
      const short8 ah1 = *(const short8*)(hlnbH + aoff1 + ka);
      const short8 al0 = *(const short8*)(hlnbL + aoff0 + ka);
      const short8 al1 = *(const short8*)(hlnbL + aoff1 + ka);
      const __hip_bfloat16* bp = wlds + (size_t)kk * 4 * 512 + lane * 8;
      short8 bh[4], bl[4];
#pragma unroll
      for (int nf = 0; nf < 4; ++nf) {
        bh[nf] = *(const short8*)(bp + nf * 512);
        bl[nf] = *(const short8*)(bp + 19 * 4 * 512 + nf * 512);
      }
#pragma unroll
      for (int nf = 0; nf < 4; ++nf) {
        acc[0][nf] = __builtin_amdgcn_mfma_f32_16x16x32_bf16(ah0, bh[nf], acc[0][nf], 0, 0, 0);
        acc[0][nf] = __builtin_amdgcn_mfma_f32_16x16x32_bf16(ah0, bl[nf], acc[0][nf], 0, 0, 0);
        acc[0][nf] = __builtin_amdgcn_mfma_f32_16x16x32_bf16(al0, bh[nf], acc[0][nf], 0, 0, 0);
        acc[0][nf] = __builtin_amdgcn_mfma_f32_16x16x32_bf16(al0, bl[nf], acc[0][nf], 0, 0, 0);
        acc[1][nf] = __builtin_amdgcn_mfma_f32_16x16x32_bf16(ah1, bh[nf], acc[1][nf], 0, 0, 0);
        acc[1][nf] = __builtin_amdgcn_mfma_f32_16x16x32_bf16(ah1, bl[nf], acc[1][nf], 0, 0, 0);
        acc[1][nf] = __builtin_amdgcn_mfma_f32_16x16x32_bf16(al1, bh[nf], acc[1][nf], 0, 0, 0);
        acc[1][nf] = __builtin_amdgcn_mfma_f32_16x16x32_bf16(al1, bl[nf], acc[1][nf], 0, 0, 0);
      }
    }
    {
      float* Cb = inner + (size_t)(d * 2 + kp) * B_ * NP;
#pragma unroll
      for (int mi = 0; mi < 2; ++mi)
#pragma unroll
        for (int nf = 0; nf < 4; ++nf) {
          const int gc = n0 + nf * 16 + (lane & 15);
          const int gr = mbase + mi * 16 + ((lane >> 4) << 2);
#pragma unroll
          for (int j = 0; j < 4; ++j)
            Cb[(size_t)(gr + j) * NP + gc] = acc[mi][nf][j];
        }
    }
    __threadfence();
    grid.sync();

    // ---------- UPDATE phase ----------
    const int t = w0 + s;
    for (int pass = 0; pass < 2; ++pass) {
      if (pass == 1 && bid >= 256 - NBLK) break;     // 24 extra rows
      const int ur = pass ? (NBLK + bid) : bid;      // 0..255
      const int ud = ur >> 7, r = ur & 127;

      const float* rec0 = inner + ((size_t)(ud * 2 + 0) * B_ + r) * NP;
      const float* rec1 = inner + ((size_t)(ud * 2 + 1) * B_ + r) * NP;
      const size_t xoff = ((size_t)(ud * WIN + s) * B_ + r) * NP;
      const __hip_bfloat16* xH = xpwH + xoff;
      const __hip_bfloat16* xL = xpwL + xoff;
      const float* rb = (ud ? bw_bias : fw_bias) + N3;
      const float* g0 = ud ? bw_ln0g : fw_ln0g;
      const float* b0 = ud ? bw_ln0b : fw_ln0b;
      const float* g3 = ud ? bw_ln3g : fw_ln3g;
      const float* b3 = ud ? bw_ln3b : fw_ln3b;
      float* hl = hln + ((size_t)ud * B_ + r) * U_;
      __hip_bfloat16* hlbH = hlnbH + ((size_t)ud * B_ + r) * KU;
      __hip_bfloat16* hlbL = hlnbL + ((size_t)ud * B_ + r) * KU;

      float zv[5], cv[5], hv[5];
      float s1 = 0.f, s2 = 0.f;
#pragma unroll
      for (int i = 0; i < 5; ++i) {
        const int c = tid + i * 256;
        if (c < U_) {
          const float xz = __bfloat162float(xH[c]) + __bfloat162float(xL[c]);
          const float xg = __bfloat162float(xH[U_ + c]) + __bfloat162float(xL[U_ + c]);
          const float xh = __bfloat162float(xH[2 * U_ + c]) + __bfloat162float(xL[2 * U_ + c]);
          const float z  = sigmf(xz + rec0[c] + rec1[c] + rb[c]);
          const float rr = sigmf(xg + rec0[U_ + c] + rec1[U_ + c] + rb[U_ + c]);
          const float cand = xh + rr * (rec0[2 * U_ + c] + rec1[2 * U_ + c] + rb[2 * U_ + c]);
          zv[i] = z; cv[i] = cand;
          s1 += cand; s2 += cand * cand;
        }
      }
      breduce2(s1, s2, red, tid);
      const float m1 = s1 / U_;
      const float is1 = rsqrtf(s2 / U_ - m1 * m1 + LN_EPS);

      float t1 = 0.f, t2 = 0.f;
#pragma unroll
      for (int i = 0; i < 5; ++i) {
        const int c = tid + i * 256;
        if (c < U_) {
          const float hh = tanhf(g3[c] * (cv[i] - m1) * is1 + b3[c]);
          const float hn = zv[i] * hl[c] + (1.f - zv[i]) * hh;
          hv[i] = hn;
          t1 += hn; t2 += hn * hn;
        }
      }
      breduce2(t1, t2, red, tid);
      const float m2 = t1 / U_;
      const float is2 = rsqrtf(t2 / U_ - m2 * m2 + LN_EPS);

#pragma unroll
      for (int i = 0; i < 5; ++i) {
        const int c = tid + i * 256;
        if (c < U_) {
          const float hlnew = g0[c] * (hv[i] - m2) * is2 + b0[c];
          hl[c] = hlnew;
          const __hip_bfloat16 hi = __float2bfloat16(hlnew);
          hlbH[c] = hi;
          hlbL[c] = __float2bfloat16(hlnew - __bfloat162float(hi));
          if (t == T_ - 1) out_tv[(size_t)r * 2400 + (size_t)ud * U_ + c] = hv[i];
        }
      }
    }
    __threadfence();
    grid.sync();
  }
}

// ---------------- host-side launch ----------------
extern "C" void kernel_launch(void* const* d_in, const int* in_sizes, int n_in,
                              void* d_out, int out_size, void* d_ws, size_t ws_size,
                              hipStream_t stream) {
  const int*   sent      = (const int*)  d_in[0];
  const float* embed     = (const float*)d_in[1];
  const float* fw_kernel = (const float*)d_in[2];
  const float* fw_rkern  = (const float*)d_in[3];
  const float* fw_bias   = (const float*)d_in[4];
  const float* fw_ln0g   = (const float*)d_in[5];
  const float* fw_ln0b   = (const float*)d_in[6];
  const float* fw_ln3g   = (const float*)d_in[7];
  const float* fw_ln3b   = (const float*)d_in[8];
  const float* bw_kernel = (const float*)d_in[9];
  const float* bw_rkern  = (const float*)d_in[10];
  const float* bw_bias   = (const float*)d_in[11];
  const float* bw_ln0g   = (const float*)d_in[12];
  const float* bw_ln0b   = (const float*)d_in[13];
  const float* bw_ln3g   = (const float*)d_in[14];
  const float* bw_ln3b   = (const float*)d_in[15];

  uint8_t* ws = (uint8_t*)d_ws;
  __hip_bfloat16* embH  = (__hip_bfloat16*)(ws + OFF_EMBH);
  __hip_bfloat16* embL  = (__hip_bfloat16*)(ws + OFF_EMBL);
  __hip_bfloat16* kTH   = (__hip_bfloat16*)(ws + OFF_KTH);
  __hip_bfloat16* kTL   = (__hip_bfloat16*)(ws + OFF_KTL);
  __hip_bfloat16* rkTH  = (__hip_bfloat16*)(ws + OFF_RKTH);
  __hip_bfloat16* rkTL  = (__hip_bfloat16*)(ws + OFF_RKTL);
  __hip_bfloat16* xpwH  = (__hip_bfloat16*)(ws + OFF_XPWH);
  __hip_bfloat16* xpwL  = (__hip_bfloat16*)(ws + OFF_XPWL);
  float*          inner = (float*)(ws + OFF_INNER);
  float*          hln   = (float*)(ws + OFF_HLN);
  __hip_bfloat16* hlnbH = (__hip_bfloat16*)(ws + OFF_HLNBH);
  __hip_bfloat16* hlnbL = (__hip_bfloat16*)(ws + OFF_HLNBL);

  float* out_tv  = (float*)d_out;                        // [128][2400]
  float* out_emb = (float*)d_out + (size_t)B_ * 2 * U_;  // [8192][620]

  // K1: embedding gather + tanh (fp32 + hi/lo bf16 planes)
  embed_kernel<<<B_ * T_, 256, 0, stream>>>(sent, embed, out_emb, embH, embL);

  // K2: weight transpose+cast hi/lo (both dirs each)
  transpose_cast<<<dim3(NP / 32, KE / 32, 2), dim3(32, 8), 0, stream>>>(
      fw_kernel, bw_kernel, kTH, kTL, E_, KE);
  transpose_cast<<<dim3(NP / 32, KU / 32, 2), dim3(32, 8), 0, stream>>>(
      fw_rkern, bw_rkern, rkTH, rkTL, U_, KU);

  // K4: h_ln = LN(0) = beta
  init_hln<<<(2 * B_ * KU + 255) / 256, 256, 0, stream>>>(fw_ln0b, bw_ln0b,
                                                          hln, hlnbH, hlnbL);

  // scan: windowed x-projection GEMM + persistent cooperative scan
  for (int w0 = 0; w0 < T_; w0 += WIN) {
    xwin_gemm<<<dim3(NP / 128, (WIN * B_) / 128, 2), 256, 0, stream>>>(
        embH, embL, kTH, kTL, fw_bias, bw_bias, xpwH, xpwL, w0);

    int w0v = w0;
    void* args[] = {
        (void*)&rkTH, (void*)&rkTL, (void*)&hlnbH, (void*)&hlnbL,
        (void*)&hln, (void*)&inner, (void*)&xpwH, (void*)&xpwL,
        (void*)&fw_bias, (void*)&bw_bias,
        (void*)&fw_ln0g, (void*)&fw_ln0b, (void*)&fw_ln3g, (void*)&fw_ln3b,
        (void*)&bw_ln0g, (void*)&bw_ln0b, (void*)&bw_ln3g, (void*)&bw_ln3b,
        (void*)&out_tv, (void*)&w0v};
    hipLaunchCooperativeKernel((const void*)scan_persist, dim3(NBLK), dim3(256),
                               args, 0, stream);
  }
}

// Round 6
// 2610.567 us; speedup vs baseline: 3.6369x; 3.6369x over previous
//
#include <hip/hip_runtime.h>
#include <hip/hip_bf16.h>

// Sizes
#define U_    1200
#define E_    620
#define B_    128
#define T_    64
#define N3    3600           // 3*U
#define NP    3712           // padded 3U = 29*128
#define KE    640            // padded E  = 10*64
#define KU    1216           // padded U  = 19*64
#define WIN   16             // xproj window (scan steps per window GEMM)
#define LN_EPS 1e-3f

typedef __attribute__((ext_vector_type(8))) short short8;
typedef __attribute__((ext_vector_type(4))) float f32x4;

// ---------------- workspace layout (bytes) ----------------
constexpr size_t OFF_EMBH  = 0;                                   // bf16 [8192][KE] hi
constexpr size_t SZ_EMB    = (size_t)8192 * KE * 2;
constexpr size_t OFF_EMBL  = OFF_EMBH + SZ_EMB;
constexpr size_t OFF_KTH   = OFF_EMBL + SZ_EMB;                   // bf16 [2][NP][KE] hi
constexpr size_t SZ_KT     = (size_t)2 * NP * KE * 2;
constexpr size_t OFF_KTL   = OFF_KTH + SZ_KT;
constexpr size_t OFF_RKTH  = OFF_KTL + SZ_KT;                     // bf16 [2][NP][KU] hi
constexpr size_t SZ_RKT    = (size_t)2 * NP * KU * 2;
constexpr size_t OFF_RKTL  = OFF_RKTH + SZ_RKT;
constexpr size_t OFF_XPWH  = OFF_RKTL + SZ_RKT;                   // bf16 [2][WIN][B][NP] hi
constexpr size_t SZ_XPW    = (size_t)2 * WIN * B_ * NP * 2;
constexpr size_t OFF_XPWL  = OFF_XPWH + SZ_XPW;
constexpr size_t OFF_INNER = OFF_XPWL + SZ_XPW;                   // f32 [2d*4kp][B][NP]
constexpr size_t SZ_INNER  = (size_t)8 * B_ * NP * 4;
constexpr size_t OFF_HLN   = OFF_INNER + SZ_INNER;                // f32 [2][B][U]
constexpr size_t SZ_HLN    = (size_t)2 * B_ * U_ * 4;
constexpr size_t OFF_HLNBH = OFF_HLN + SZ_HLN;                    // bf16 [2][B][KU] hi
constexpr size_t SZ_HLNB   = (size_t)2 * B_ * KU * 2;
constexpr size_t OFF_HLNBL = OFF_HLNBH + SZ_HLNB;

__device__ inline void lds_load16(const void* g, void* l) {
  __builtin_amdgcn_global_load_lds(
      (const __attribute__((address_space(1))) unsigned int*)g,
      (__attribute__((address_space(3))) unsigned int*)l, 16, 0, 0);
}

__device__ inline float sigmf(float x) { return 1.f / (1.f + expf(-x)); }

// ---------------- K1: embedding gather + tanh (fp32 out + hi/lo bf16) -----
__global__ __launch_bounds__(256)
void embed_kernel(const int* __restrict__ sent, const float* __restrict__ embed,
                  float* __restrict__ out_emb,
                  __hip_bfloat16* __restrict__ embH, __hip_bfloat16* __restrict__ embL) {
  const int row = blockIdx.x;                 // b*T + t
  const int idx = sent[row];
  const float* src = embed + (size_t)idx * E_;
  for (int e = threadIdx.x; e < KE; e += 256) {
    float v = 0.f;
    if (e < E_) {
      v = tanhf(src[e]);
      out_emb[(size_t)row * E_ + e] = v;
    }
    const __hip_bfloat16 hi = __float2bfloat16(v);
    embH[(size_t)row * KE + e] = hi;
    embL[(size_t)row * KE + e] = __float2bfloat16(v - __bfloat162float(hi));
  }
}

// ---------------- K2: transpose+cast [K][3600]f32 -> [NP][Kp] hi/lo bf16 ---
__global__ __launch_bounds__(256)
void transpose_cast(const float* __restrict__ W0, const float* __restrict__ W1,
                    __hip_bfloat16* __restrict__ WtHi, __hip_bfloat16* __restrict__ WtLo,
                    int Kreal, int Kp) {
  const int d = blockIdx.z;
  const float* W = d ? W1 : W0;
  __hip_bfloat16* dstH = WtHi + (size_t)d * NP * Kp;
  __hip_bfloat16* dstL = WtLo + (size_t)d * NP * Kp;
  __shared__ float tile[32][33];
  const int n0 = blockIdx.x * 32, k0 = blockIdx.y * 32;
  const int tx = threadIdx.x, ty = threadIdx.y;   // 32 x 8
#pragma unroll
  for (int i = 0; i < 32; i += 8) {
    const int k = k0 + ty + i, n = n0 + tx;
    tile[ty + i][tx] = (k < Kreal && n < N3) ? W[(size_t)k * N3 + n] : 0.f;
  }
  __syncthreads();
#pragma unroll
  for (int i = 0; i < 32; i += 8) {
    const int n = n0 + ty + i, k = k0 + tx;
    const float v = tile[tx][ty + i];
    const __hip_bfloat16 hi = __float2bfloat16(v);
    dstH[(size_t)n * Kp + k] = hi;
    dstL[(size_t)n * Kp + k] = __float2bfloat16(v - __bfloat162float(hi));
  }
}

// ---------------- K4: init h_ln = LN(0) = beta ----------------
__global__ __launch_bounds__(256)
void init_hln(const float* __restrict__ fw_b0, const float* __restrict__ bw_b0,
              float* __restrict__ hln, __hip_bfloat16* __restrict__ hlnbH,
              __hip_bfloat16* __restrict__ hlnbL) {
  const int idx = blockIdx.x * 256 + threadIdx.x;   // [2*128*KU]
  if (idx >= 2 * B_ * KU) return;
  const int k = idx % KU;
  const int rowd = idx / KU;
  const int d = rowd >> 7;
  float v = 0.f;
  if (k < U_) {
    v = (d ? bw_b0 : fw_b0)[k];
    hln[(size_t)rowd * U_ + k] = v;
  }
  const __hip_bfloat16 hi = __float2bfloat16(v);
  hlnbH[idx] = hi;
  hlnbL[idx] = __float2bfloat16(v - __bfloat162float(hi));
}

// Swizzle helpers: LDS tiles are [rows][64 bf16]. Stage pre-swizzles the
// GLOBAL column (source permutation), reads XOR the in-row byte offset —
// same involution on both sides (rule 21). Breaks the stride-128B 16-way
// bank conflict down to 2-way (free).
__device__ inline int swz_scol(int tid) {           // staged col group (elems)
  return (((tid & 7) ^ ((tid >> 3) & 7)) << 3);
}
__device__ inline int swz_off(int row, int kk, int lane) {  // read offset (elems)
  return row * 64 + ((kk * 32 + ((lane >> 4) << 3)) ^ ((row & 7) << 3));
}

// ---------------- window GEMM: x+ib for WIN scan steps, hi/lo out ---------
// Flat grid 928 = 8 XCD * 116; bijective remap gives each XCD a contiguous
// n-panel slice (L2-resident weights, reused by all 16 m-tiles).
__global__ __launch_bounds__(256)
void xwin_gemm(const __hip_bfloat16* __restrict__ embH, const __hip_bfloat16* __restrict__ embL,
               const __hip_bfloat16* __restrict__ kTH, const __hip_bfloat16* __restrict__ kTL,
               const float* __restrict__ fw_bias, const float* __restrict__ bw_bias,
               __hip_bfloat16* __restrict__ xpwH, __hip_bfloat16* __restrict__ xpwL,
               int w0) {
  constexpr int BM = 128, BN = 128, BK = 64;
  constexpr int WM = 64, WN = 64, FM = 4, FN = 4;
  constexpr int TA = BM * BK, TB = BN * BK;       // 8192 elems
  const int bid = blockIdx.x;
  const int w = (bid & 7) * 116 + (bid >> 3);     // bijective: 928 = 8*116
  const int d = w / 464;
  const int q = w % 464;
  const int nt = q / 16, mt = q % 16;
  const int m0 = mt * BM;
  const int n0 = nt * BN;

  const __hip_bfloat16* BH = kTH + (size_t)d * NP * KE;
  const __hip_bfloat16* BL = kTL + (size_t)d * NP * KE;

  const int tid = threadIdx.x;
  const int lane = tid & 63;
  const int wid = tid >> 6;
  const int wr = wid >> 1, wc = wid & 1;

  __shared__ __align__(16) __hip_bfloat16 As[2 * TA];
  __shared__ __align__(16) __hip_bfloat16 Bs[2 * TB];

  f32x4 acc[FM][FN] = {};

  const int srow = tid >> 3;
  const int scol = swz_scol(tid);

  for (int ks = 0; ks < KE / BK; ++ks) {
    const int k0 = ks * BK;
    __syncthreads();
#pragma unroll
    for (int it = 0; it < TA / 2048; ++it) {
      const int row = m0 + it * 32 + srow;       // m index
      const int b = row & 127, srel = row >> 7;
      const int txi = d ? (T_ - 1 - (w0 + srel)) : (w0 + srel);
      const size_t goff = (size_t)(b * T_ + txi) * KE + k0 + scol;
      lds_load16(embH + goff, As + it * 2048 + tid * 8);
      lds_load16(embL + goff, As + TA + it * 2048 + tid * 8);
    }
#pragma unroll
    for (int it = 0; it < TB / 2048; ++it) {
      const size_t goff = (size_t)(n0 + it * 32 + srow) * KE + k0 + scol;
      lds_load16(BH + goff, Bs + it * 2048 + tid * 8);
      lds_load16(BL + goff, Bs + TB + it * 2048 + tid * 8);
    }
    __syncthreads();
#pragma unroll
    for (int kk = 0; kk < BK / 32; ++kk) {
      short8 ah[FM], al[FM], bh[FN], bl[FN];
#pragma unroll
      for (int mi = 0; mi < FM; ++mi) {
        const int row = wr * WM + mi * 16 + (lane & 15);
        const int off = swz_off(row, kk, lane);
        ah[mi] = *(const short8*)(As + off);
        al[mi] = *(const short8*)(As + TA + off);
      }
#pragma unroll
      for (int ni = 0; ni < FN; ++ni) {
        const int row = wc * WN + ni * 16 + (lane & 15);
        const int off = swz_off(row, kk, lane);
        bh[ni] = *(const short8*)(Bs + off);
        bl[ni] = *(const short8*)(Bs + TB + off);
      }
#pragma unroll
      for (int mi = 0; mi < FM; ++mi)
#pragma unroll
        for (int ni = 0; ni < FN; ++ni) {
          acc[mi][ni] = __builtin_amdgcn_mfma_f32_16x16x32_bf16(ah[mi], bh[ni], acc[mi][ni], 0, 0, 0);
          acc[mi][ni] = __builtin_amdgcn_mfma_f32_16x16x32_bf16(ah[mi], bl[ni], acc[mi][ni], 0, 0, 0);
          acc[mi][ni] = __builtin_amdgcn_mfma_f32_16x16x32_bf16(al[mi], bh[ni], acc[mi][ni], 0, 0, 0);
        }
    }
  }

  const float* ib = d ? bw_bias : fw_bias;
#pragma unroll
  for (int mi = 0; mi < FM; ++mi)
#pragma unroll
    for (int ni = 0; ni < FN; ++ni) {
      const int gc = n0 + wc * WN + ni * 16 + (lane & 15);
      const float bv = (gc < N3) ? ib[gc] : 0.f;
      const int gr0 = m0 + wr * WM + mi * 16 + ((lane >> 4) << 2);
#pragma unroll
      for (int j = 0; j < 4; ++j) {
        const int gr = gr0 + j;
        const int b = gr & 127, srel = gr >> 7;
        const size_t off = ((size_t)(d * WIN + srel) * B_ + b) * NP + gc;
        const float v = acc[mi][ni][j] + bv;
        const __hip_bfloat16 hi = __float2bfloat16(v);
        xpwH[off] = hi;
        xpwL[off] = __float2bfloat16(v - __bfloat162float(hi));
      }
    }
}

// ---------------- per-step rec GEMM: split-K x4, dbuf, A-direct -----------
// Flat 928 blocks = 8 XCD * 116; remap pins each (d,kp) weight slab (4.5 MB)
// to one XCD's L2 across all 64 step launches. B staged hi/lo to swizzled
// LDS (double-buffered, STAGE-next-before-compute); A-frags read directly
// from global (L2-hot). 4-term split precision.
__global__ __launch_bounds__(256)
void step_rec(const __hip_bfloat16* __restrict__ hlnbH, const __hip_bfloat16* __restrict__ hlnbL,
              const __hip_bfloat16* __restrict__ rkTH, const __hip_bfloat16* __restrict__ rkTL,
              float* __restrict__ inner) {
  const int bid = blockIdx.x;
  const int w = (bid & 7) * 116 + (bid >> 3);     // bijective: 928 = 8*116
  const int m  = w & 1;
  const int q  = w >> 1;                          // 0..463
  const int nt = q % 58;
  const int z  = q / 58;                          // 0..7 = d*4+kp
  const int d  = z >> 2, kp = z & 3;
  const int ks0 = kp * 5;
  const int ks1 = (kp == 3) ? 19 : (ks0 + 5);
  const int n0 = nt * 64;
  const int m0 = m * 64;

  const int tid = threadIdx.x;
  const int lane = tid & 63;
  const int wid = tid >> 6;
  const int wr = wid >> 1, wc = wid & 1;

  const __hip_bfloat16* WH = rkTH + (size_t)d * NP * KU;
  const __hip_bfloat16* WL = rkTL + (size_t)d * NP * KU;

  __shared__ __align__(16) __hip_bfloat16 Bs[2][2][4096];   // [buf][plane][64x64]

  const int srow = tid >> 3;
  const int scol = swz_scol(tid);

  // A-fragment base: row = m0 + wr*32 + (lane&15), col = (lane>>4)*8
  const size_t arow0 = (size_t)(d * B_ + m0 + wr * 32 + (lane & 15)) * KU + ((lane >> 4) << 3);

  f32x4 acc[2][2] = {};

#define STAGE_B(buf, ks)                                                       \
  {                                                                            \
    const size_t kc = (size_t)(ks) * 64 + scol;                                \
    _Pragma("unroll")                                                          \
    for (int it = 0; it < 2; ++it) {                                           \
      const size_t g = (size_t)(n0 + it * 32 + srow) * KU + kc;                \
      lds_load16(WH + g, &Bs[buf][0][it * 2048 + tid * 8]);                    \
      lds_load16(WL + g, &Bs[buf][1][it * 2048 + tid * 8]);                    \
    }                                                                          \
  }

  STAGE_B(0, ks0);
  __syncthreads();
  int cur = 0;
  for (int ks = ks0; ks < ks1; ++ks) {
    if (ks + 1 < ks1) STAGE_B(cur ^ 1, ks + 1);
    const size_t ab = arow0 + (size_t)ks * 64;
    short8 ah[2][2], al[2][2];                    // [mi][kk]
#pragma unroll
    for (int mi = 0; mi < 2; ++mi)
#pragma unroll
      for (int kk = 0; kk < 2; ++kk) {
        const size_t a = ab + (size_t)mi * 16 * KU + kk * 32;
        ah[mi][kk] = *(const short8*)(hlnbH + a);
        al[mi][kk] = *(const short8*)(hlnbL + a);
      }
#pragma unroll
    for (int kk = 0; kk < 2; ++kk) {
      short8 bh[2], bl[2];
#pragma unroll
      for (int nf = 0; nf < 2; ++nf) {
        const int row = wc * 32 + nf * 16 + (lane & 15);
        const int off = swz_off(row, kk, lane);
        bh[nf] = *(const short8*)(&Bs[cur][0][off]);
        bl[nf] = *(const short8*)(&Bs[cur][1][off]);
      }
#pragma unroll
      for (int mi = 0; mi < 2; ++mi)
#pragma unroll
        for (int nf = 0; nf < 2; ++nf) {
          acc[mi][nf] = __builtin_amdgcn_mfma_f32_16x16x32_bf16(ah[mi][kk], bh[nf], acc[mi][nf], 0, 0, 0);
          acc[mi][nf] = __builtin_amdgcn_mfma_f32_16x16x32_bf16(ah[mi][kk], bl[nf], acc[mi][nf], 0, 0, 0);
          acc[mi][nf] = __builtin_amdgcn_mfma_f32_16x16x32_bf16(al[mi][kk], bh[nf], acc[mi][nf], 0, 0, 0);
          acc[mi][nf] = __builtin_amdgcn_mfma_f32_16x16x32_bf16(al[mi][kk], bl[nf], acc[mi][nf], 0, 0, 0);
        }
    }
    __syncthreads();
    cur ^= 1;
  }
#undef STAGE_B

  float* C = inner + (size_t)z * B_ * NP;
#pragma unroll
  for (int mi = 0; mi < 2; ++mi)
#pragma unroll
    for (int nf = 0; nf < 2; ++nf) {
      const int gc = n0 + wc * 32 + nf * 16 + (lane & 15);
      const int gr = m0 + wr * 32 + mi * 16 + ((lane >> 4) << 2);
#pragma unroll
      for (int j = 0; j < 4; ++j)
        C[(size_t)(gr + j) * NP + gc] = acc[mi][nf][j];
    }
}

// ---------------- block-wide 2-value sum reduction ----------------
__device__ inline void breduce2(float& a, float& b, float* red, int tid) {
#pragma unroll
  for (int off = 32; off; off >>= 1) {
    a += __shfl_down(a, off, 64);
    b += __shfl_down(b, off, 64);
  }
  const int w = tid >> 6;
  __syncthreads();
  if ((tid & 63) == 0) { red[w] = a; red[4 + w] = b; }
  __syncthreads();
  a = red[0] + red[1] + red[2] + red[3];
  b = red[4] + red[5] + red[6] + red[7];
}

// ---------------- K6: per-row GRU update (one block per (dir,row)) --------
__global__ __launch_bounds__(256)
void gru_update(const float* __restrict__ inner,
                const __hip_bfloat16* __restrict__ xpwH, const __hip_bfloat16* __restrict__ xpwL,
                const float* __restrict__ fw_bias, const float* __restrict__ bw_bias,
                const float* __restrict__ fw_ln0g, const float* __restrict__ fw_ln0b,
                const float* __restrict__ fw_ln3g, const float* __restrict__ fw_ln3b,
                const float* __restrict__ bw_ln0g, const float* __restrict__ bw_ln0b,
                const float* __restrict__ bw_ln3g, const float* __restrict__ bw_ln3b,
                float* __restrict__ hln, __hip_bfloat16* __restrict__ hlnbH,
                __hip_bfloat16* __restrict__ hlnbL,
                float* __restrict__ out_tv, int srel, int t) {
  const int bid = blockIdx.x;
  const int d = bid >> 7;
  const int r = bid & 127;
  const int tid = threadIdx.x;

  const float* rec0 = inner + ((size_t)(d * 4 + 0) * B_ + r) * NP;
  const float* rec1 = inner + ((size_t)(d * 4 + 1) * B_ + r) * NP;
  const float* rec2 = inner + ((size_t)(d * 4 + 2) * B_ + r) * NP;
  const float* rec3 = inner + ((size_t)(d * 4 + 3) * B_ + r) * NP;
  const size_t xoff = ((size_t)(d * WIN + srel) * B_ + r) * NP;
  const __hip_bfloat16* xH = xpwH + xoff;
  const __hip_bfloat16* xL = xpwL + xoff;
  const float* rb = (d ? bw_bias : fw_bias) + N3;
  const float* g0 = d ? bw_ln0g : fw_ln0g;
  const float* b0 = d ? bw_ln0b : fw_ln0b;
  const float* g3 = d ? bw_ln3g : fw_ln3g;
  const float* b3 = d ? bw_ln3b : fw_ln3b;
  float* hl = hln + ((size_t)d * B_ + r) * U_;
  __hip_bfloat16* hlbH = hlnbH + ((size_t)d * B_ + r) * KU;
  __hip_bfloat16* hlbL = hlnbL + ((size_t)d * B_ + r) * KU;

  __shared__ float red[8];

  float zv[5], cv[5], hv[5];
  float s1 = 0.f, s2 = 0.f;
#pragma unroll
  for (int i = 0; i < 5; ++i) {
    const int c = tid + i * 256;
    if (c < U_) {
      const float xz = __bfloat162float(xH[c]) + __bfloat162float(xL[c]);
      const float xg = __bfloat162float(xH[U_ + c]) + __bfloat162float(xL[U_ + c]);
      const float xh = __bfloat162float(xH[2 * U_ + c]) + __bfloat162float(xL[2 * U_ + c]);
      const float rz = (rec0[c] + rec1[c]) + (rec2[c] + rec3[c]);
      const float rg = (rec0[U_ + c] + rec1[U_ + c]) + (rec2[U_ + c] + rec3[U_ + c]);
      const float rh = (rec0[2 * U_ + c] + rec1[2 * U_ + c]) + (rec2[2 * U_ + c] + rec3[2 * U_ + c]);
      const float z  = sigmf(xz + rz + rb[c]);
      const float rr = sigmf(xg + rg + rb[U_ + c]);
      const float cand = xh + rr * (rh + rb[2 * U_ + c]);
      zv[i] = z; cv[i] = cand;
      s1 += cand; s2 += cand * cand;
    }
  }
  breduce2(s1, s2, red, tid);
  const float m1 = s1 / U_;
  const float is1 = rsqrtf(s2 / U_ - m1 * m1 + LN_EPS);

  float t1 = 0.f, t2 = 0.f;
#pragma unroll
  for (int i = 0; i < 5; ++i) {
    const int c = tid + i * 256;
    if (c < U_) {
      const float hh = tanhf(g3[c] * (cv[i] - m1) * is1 + b3[c]);
      const float hn = zv[i] * hl[c] + (1.f - zv[i]) * hh;
      hv[i] = hn;
      t1 += hn; t2 += hn * hn;
    }
  }
  breduce2(t1, t2, red, tid);
  const float m2 = t1 / U_;
  const float is2 = rsqrtf(t2 / U_ - m2 * m2 + LN_EPS);

#pragma unroll
  for (int i = 0; i < 5; ++i) {
    const int c = tid + i * 256;
    if (c < U_) {
      const float hlnew = g0[c] * (hv[i] - m2) * is2 + b0[c];
      hl[c] = hlnew;
      const __hip_bfloat16 hi = __float2bfloat16(hlnew);
      hlbH[c] = hi;
      hlbL[c] = __float2bfloat16(hlnew - __bfloat162float(hi));
      if (t == T_ - 1) out_tv[(size_t)r * 2400 + (size_t)d * U_ + c] = hv[i];
    }
  }
}

// ---------------- host-side launch ----------------
extern "C" void kernel_launch(void* const* d_in, const int* in_sizes, int n_in,
                              void* d_out, int out_size, void* d_ws, size_t ws_size,
                              hipStream_t stream) {
  const int*   sent      = (const int*)  d_in[0];
  const float* embed     = (const float*)d_in[1];
  const float* fw_kernel = (const float*)d_in[2];
  const float* fw_rkern  = (const float*)d_in[3];
  const float* fw_bias   = (const float*)d_in[4];
  const float* fw_ln0g   = (const float*)d_in[5];
  const float* fw_ln0b   = (const float*)d_in[6];
  const float* fw_ln3g   = (const float*)d_in[7];
  const float* fw_ln3b   = (const float*)d_in[8];
  const float* bw_kernel = (const float*)d_in[9];
  const float* bw_rkern  = (const float*)d_in[10];
  const float* bw_bias   = (const float*)d_in[11];
  const float* bw_ln0g   = (const float*)d_in[12];
  const float* bw_ln0b   = (const float*)d_in[13];
  const float* bw_ln3g   = (const float*)d_in[14];
  const float* bw_ln3b   = (const float*)d_in[15];

  uint8_t* ws = (uint8_t*)d_ws;
  __hip_bfloat16* embH  = (__hip_bfloat16*)(ws + OFF_EMBH);
  __hip_bfloat16* embL  = (__hip_bfloat16*)(ws + OFF_EMBL);
  __hip_bfloat16* kTH   = (__hip_bfloat16*)(ws + OFF_KTH);
  __hip_bfloat16* kTL   = (__hip_bfloat16*)(ws + OFF_KTL);
  __hip_bfloat16* rkTH  = (__hip_bfloat16*)(ws + OFF_RKTH);
  __hip_bfloat16* rkTL  = (__hip_bfloat16*)(ws + OFF_RKTL);
  __hip_bfloat16* xpwH  = (__hip_bfloat16*)(ws + OFF_XPWH);
  __hip_bfloat16* xpwL  = (__hip_bfloat16*)(ws + OFF_XPWL);
  float*          inner = (float*)(ws + OFF_INNER);
  float*          hln   = (float*)(ws + OFF_HLN);
  __hip_bfloat16* hlnbH = (__hip_bfloat16*)(ws + OFF_HLNBH);
  __hip_bfloat16* hlnbL = (__hip_bfloat16*)(ws + OFF_HLNBL);

  float* out_tv  = (float*)d_out;                        // [128][2400]
  float* out_emb = (float*)d_out + (size_t)B_ * 2 * U_;  // [8192][620]

  // K1: embedding gather + tanh (fp32 + hi/lo bf16 planes)
  embed_kernel<<<B_ * T_, 256, 0, stream>>>(sent, embed, out_emb, embH, embL);

  // K2: weight transpose+cast hi/lo (both dirs each)
  transpose_cast<<<dim3(NP / 32, KE / 32, 2), dim3(32, 8), 0, stream>>>(
      fw_kernel, bw_kernel, kTH, kTL, E_, KE);
  transpose_cast<<<dim3(NP / 32, KU / 32, 2), dim3(32, 8), 0, stream>>>(
      fw_rkern, bw_rkern, rkTH, rkTL, U_, KU);

  // K4: h_ln = LN(0) = beta
  init_hln<<<(2 * B_ * KU + 255) / 256, 256, 0, stream>>>(fw_ln0b, bw_ln0b,
                                                          hln, hlnbH, hlnbL);

  // scan: windowed x-projection + per-step rec GEMM (split-K4, dbuf) + update
  for (int w0 = 0; w0 < T_; w0 += WIN) {
    xwin_gemm<<<928, 256, 0, stream>>>(
        embH, embL, kTH, kTL, fw_bias, bw_bias, xpwH, xpwL, w0);
    for (int s = 0; s < WIN; ++s) {
      const int t = w0 + s;
      step_rec<<<928, 256, 0, stream>>>(hlnbH, hlnbL, rkTH, rkTL, inner);
      gru_update<<<2 * B_, 256, 0, stream>>>(
          inner, xpwH, xpwL, fw_bias, bw_bias,
          fw_ln0g, fw_ln0b, fw_ln3g, fw_ln3b,
          bw_ln0g, bw_ln0b, bw_ln3g, bw_ln3b,
          hln, hlnbH, hlnbL, out_tv, s, t);
    }
  }
}

// Round 7
// 2031.563 us; speedup vs baseline: 4.6735x; 1.2850x over previous
//
#include <hip/hip_runtime.h>
#include <hip/hip_bf16.h>

// Sizes
#define U_    1200
#define E_    620
#define B_    128
#define T_    64
#define N3    3600           // 3*U
#define NP    3712           // padded 3U = 29*128
#define KE    640            // padded E  = 10*64
#define KU    1216           // padded U  = 19*64
#define WIN   16             // xproj window (scan steps per window GEMM)
#define LN_EPS 1e-3f

#define GBLK  464            // GEMM blocks per launch (8 xcd * 58)
#define UBLK  128            // update blocks per launch
#define TBLK  (GBLK + UBLK)  // 592

typedef __attribute__((ext_vector_type(8))) short short8;
typedef __attribute__((ext_vector_type(4))) float f32x4;

// ---------------- workspace layout (bytes) ----------------
constexpr size_t OFF_EMBH  = 0;                                   // bf16 [8192][KE] hi
constexpr size_t SZ_EMB    = (size_t)8192 * KE * 2;
constexpr size_t OFF_EMBL  = OFF_EMBH + SZ_EMB;
constexpr size_t OFF_KTH   = OFF_EMBL + SZ_EMB;                   // bf16 [2][NP][KE] hi
constexpr size_t SZ_KT     = (size_t)2 * NP * KE * 2;
constexpr size_t OFF_KTL   = OFF_KTH + SZ_KT;
constexpr size_t OFF_RKTH  = OFF_KTL + SZ_KT;                     // bf16 [2][NP][KU] hi
constexpr size_t SZ_RKT    = (size_t)2 * NP * KU * 2;
constexpr size_t OFF_RKTL  = OFF_RKTH + SZ_RKT;
constexpr size_t OFF_XPWH  = OFF_RKTL + SZ_RKT;                   // bf16 [2][WIN][B][NP] hi
constexpr size_t SZ_XPW    = (size_t)2 * WIN * B_ * NP * 2;
constexpr size_t OFF_XPWL  = OFF_XPWH + SZ_XPW;
constexpr size_t OFF_INNER = OFF_XPWL + SZ_XPW;                   // f32 [2d*4kp][B][NP]
constexpr size_t SZ_INNER  = (size_t)8 * B_ * NP * 4;
constexpr size_t OFF_HLN   = OFF_INNER + SZ_INNER;                // f32 [2][B][U]
constexpr size_t SZ_HLN    = (size_t)2 * B_ * U_ * 4;
constexpr size_t OFF_HLNBH = OFF_HLN + SZ_HLN;                    // bf16 [2][B][KU] hi
constexpr size_t SZ_HLNB   = (size_t)2 * B_ * KU * 2;
constexpr size_t OFF_HLNBL = OFF_HLNBH + SZ_HLNB;

__device__ inline void lds_load16(const void* g, void* l) {
  __builtin_amdgcn_global_load_lds(
      (const __attribute__((address_space(1))) unsigned int*)g,
      (__attribute__((address_space(3))) unsigned int*)l, 16, 0, 0);
}

__device__ inline float sigmf(float x) { return 1.f / (1.f + expf(-x)); }

// Swizzle helpers (verified r6: 0 bank conflicts). LDS tiles [rows][64 bf16];
// stage pre-swizzles the GLOBAL column group, read XORs the in-row offset.
__device__ inline int swz_scol(int tid) {
  return (((tid & 7) ^ ((tid >> 3) & 7)) << 3);
}
__device__ inline int swz_off(int row, int kk, int lane) {
  return row * 64 + ((kk * 32 + ((lane >> 4) << 3)) ^ ((row & 7) << 3));
}

// ---------------- K1: embedding gather + tanh (fp32 out + hi/lo bf16) -----
__global__ __launch_bounds__(256)
void embed_kernel(const int* __restrict__ sent, const float* __restrict__ embed,
                  float* __restrict__ out_emb,
                  __hip_bfloat16* __restrict__ embH, __hip_bfloat16* __restrict__ embL) {
  const int row = blockIdx.x;                 // b*T + t
  const int idx = sent[row];
  const float* src = embed + (size_t)idx * E_;
  for (int e = threadIdx.x; e < KE; e += 256) {
    float v = 0.f;
    if (e < E_) {
      v = tanhf(src[e]);
      out_emb[(size_t)row * E_ + e] = v;
    }
    const __hip_bfloat16 hi = __float2bfloat16(v);
    embH[(size_t)row * KE + e] = hi;
    embL[(size_t)row * KE + e] = __float2bfloat16(v - __bfloat162float(hi));
  }
}

// ---------------- K2: transpose+cast [K][3600]f32 -> [NP][Kp] hi/lo bf16 ---
__global__ __launch_bounds__(256)
void transpose_cast(const float* __restrict__ W0, const float* __restrict__ W1,
                    __hip_bfloat16* __restrict__ WtHi, __hip_bfloat16* __restrict__ WtLo,
                    int Kreal, int Kp) {
  const int d = blockIdx.z;
  const float* W = d ? W1 : W0;
  __hip_bfloat16* dstH = WtHi + (size_t)d * NP * Kp;
  __hip_bfloat16* dstL = WtLo + (size_t)d * NP * Kp;
  __shared__ float tile[32][33];
  const int n0 = blockIdx.x * 32, k0 = blockIdx.y * 32;
  const int tx = threadIdx.x, ty = threadIdx.y;   // 32 x 8
#pragma unroll
  for (int i = 0; i < 32; i += 8) {
    const int k = k0 + ty + i, n = n0 + tx;
    tile[ty + i][tx] = (k < Kreal && n < N3) ? W[(size_t)k * N3 + n] : 0.f;
  }
  __syncthreads();
#pragma unroll
  for (int i = 0; i < 32; i += 8) {
    const int n = n0 + ty + i, k = k0 + tx;
    const float v = tile[tx][ty + i];
    const __hip_bfloat16 hi = __float2bfloat16(v);
    dstH[(size_t)n * Kp + k] = hi;
    dstL[(size_t)n * Kp + k] = __float2bfloat16(v - __bfloat162float(hi));
  }
}

// ---------------- K4: init h_ln = LN(0) = beta ----------------
__global__ __launch_bounds__(256)
void init_hln(const float* __restrict__ fw_b0, const float* __restrict__ bw_b0,
              float* __restrict__ hln, __hip_bfloat16* __restrict__ hlnbH,
              __hip_bfloat16* __restrict__ hlnbL) {
  const int idx = blockIdx.x * 256 + threadIdx.x;   // [2*128*KU]
  if (idx >= 2 * B_ * KU) return;
  const int k = idx % KU;
  const int rowd = idx / KU;
  const int d = rowd >> 7;
  float v = 0.f;
  if (k < U_) {
    v = (d ? bw_b0 : fw_b0)[k];
    hln[(size_t)rowd * U_ + k] = v;
  }
  const __hip_bfloat16 hi = __float2bfloat16(v);
  hlnbH[idx] = hi;
  hlnbL[idx] = __float2bfloat16(v - __bfloat162float(hi));
}

// ---------------- window GEMM: x+ib for WIN scan steps, hi/lo out ---------
// (unchanged from round 6: swizzled, 0 conflicts, XCD-remapped)
__global__ __launch_bounds__(256)
void xwin_gemm(const __hip_bfloat16* __restrict__ embH, const __hip_bfloat16* __restrict__ embL,
               const __hip_bfloat16* __restrict__ kTH, const __hip_bfloat16* __restrict__ kTL,
               const float* __restrict__ fw_bias, const float* __restrict__ bw_bias,
               __hip_bfloat16* __restrict__ xpwH, __hip_bfloat16* __restrict__ xpwL,
               int w0) {
  constexpr int BM = 128, BN = 128, BK = 64;
  constexpr int WM = 64, WN = 64, FM = 4, FN = 4;
  constexpr int TA = BM * BK, TB = BN * BK;       // 8192 elems
  const int bid = blockIdx.x;
  const int w = (bid & 7) * 116 + (bid >> 3);     // bijective: 928 = 8*116
  const int d = w / 464;
  const int q = w % 464;
  const int nt = q / 16, mt = q % 16;
  const int m0 = mt * BM;
  const int n0 = nt * BN;

  const __hip_bfloat16* BH = kTH + (size_t)d * NP * KE;
  const __hip_bfloat16* BL = kTL + (size_t)d * NP * KE;

  const int tid = threadIdx.x;
  const int lane = tid & 63;
  const int wid = tid >> 6;
  const int wr = wid >> 1, wc = wid & 1;

  __shared__ __align__(16) __hip_bfloat16 As[2 * TA];
  __shared__ __align__(16) __hip_bfloat16 Bs[2 * TB];

  f32x4 acc[FM][FN] = {};

  const int srow = tid >> 3;
  const int scol = swz_scol(tid);

  for (int ks = 0; ks < KE / BK; ++ks) {
    const int k0 = ks * BK;
    __syncthreads();
#pragma unroll
    for (int it = 0; it < TA / 2048; ++it) {
      const int row = m0 + it * 32 + srow;       // m index
      const int b = row & 127, srel = row >> 7;
      const int txi = d ? (T_ - 1 - (w0 + srel)) : (w0 + srel);
      const size_t goff = (size_t)(b * T_ + txi) * KE + k0 + scol;
      lds_load16(embH + goff, As + it * 2048 + tid * 8);
      lds_load16(embL + goff, As + TA + it * 2048 + tid * 8);
    }
#pragma unroll
    for (int it = 0; it < TB / 2048; ++it) {
      const size_t goff = (size_t)(n0 + it * 32 + srow) * KE + k0 + scol;
      lds_load16(BH + goff, Bs + it * 2048 + tid * 8);
      lds_load16(BL + goff, Bs + TB + it * 2048 + tid * 8);
    }
    __syncthreads();
#pragma unroll
    for (int kk = 0; kk < BK / 32; ++kk) {
      short8 ah[FM], al[FM], bh[FN], bl[FN];
#pragma unroll
      for (int mi = 0; mi < FM; ++mi) {
        const int row = wr * WM + mi * 16 + (lane & 15);
        const int off = swz_off(row, kk, lane);
        ah[mi] = *(const short8*)(As + off);
        al[mi] = *(const short8*)(As + TA + off);
      }
#pragma unroll
      for (int ni = 0; ni < FN; ++ni) {
        const int row = wc * WN + ni * 16 + (lane & 15);
        const int off = swz_off(row, kk, lane);
        bh[ni] = *(const short8*)(Bs + off);
        bl[ni] = *(const short8*)(Bs + TB + off);
      }
#pragma unroll
      for (int mi = 0; mi < FM; ++mi)
#pragma unroll
        for (int ni = 0; ni < FN; ++ni) {
          acc[mi][ni] = __builtin_amdgcn_mfma_f32_16x16x32_bf16(ah[mi], bh[ni], acc[mi][ni], 0, 0, 0);
          acc[mi][ni] = __builtin_amdgcn_mfma_f32_16x16x32_bf16(ah[mi], bl[ni], acc[mi][ni], 0, 0, 0);
          acc[mi][ni] = __builtin_amdgcn_mfma_f32_16x16x32_bf16(al[mi], bh[ni], acc[mi][ni], 0, 0, 0);
        }
    }
  }

  const float* ib = d ? bw_bias : fw_bias;
#pragma unroll
  for (int mi = 0; mi < FM; ++mi)
#pragma unroll
    for (int ni = 0; ni < FN; ++ni) {
      const int gc = n0 + wc * WN + ni * 16 + (lane & 15);
      const float bv = (gc < N3) ? ib[gc] : 0.f;
      const int gr0 = m0 + wr * WM + mi * 16 + ((lane >> 4) << 2);
#pragma unroll
      for (int j = 0; j < 4; ++j) {
        const int gr = gr0 + j;
        const int b = gr & 127, srel = gr >> 7;
        const size_t off = ((size_t)(d * WIN + srel) * B_ + b) * NP + gc;
        const float v = acc[mi][ni][j] + bv;
        const __hip_bfloat16 hi = __float2bfloat16(v);
        xpwH[off] = hi;
        xpwL[off] = __float2bfloat16(v - __bfloat162float(hi));
      }
    }
}

// ---------------- block-wide 2-value sum reduction ----------------
__device__ inline void breduce2(float& a, float& b, float* red, int tid) {
#pragma unroll
  for (int off = 32; off; off >>= 1) {
    a += __shfl_down(a, off, 64);
    b += __shfl_down(b, off, 64);
  }
  const int w = tid >> 6;
  __syncthreads();
  if ((tid & 63) == 0) { red[w] = a; red[4 + w] = b; }
  __syncthreads();
  a = red[0] + red[1] + red[2] + red[3];
  b = red[4] + red[5] + red[6] + red[7];
}

// ---------------- fused scan step: GEMM(dG,t) || UPDATE(dU,tU) ------------
// Blocks [0,464): r4-proven GEMM loop (stage A+B via global_load_lds,
// sync-stage-sync-compute) + swizzle + 3-term split, split-K4.
// XCD decode keeps both m-tiles of the same weight cols on one XCD ->
// 2.25 MB weight slab per XCD, L2-resident across all 64 steps.
// Blocks [464,592): per-row GRU update for the OTHER direction's previous
// GEMM (dep crosses the launch boundary; inside one launch dirs differ).
__global__ __launch_bounds__(256)
void step_fused(const __hip_bfloat16* __restrict__ rkTH, const __hip_bfloat16* __restrict__ rkTL,
                __hip_bfloat16* __restrict__ hlnbH, __hip_bfloat16* __restrict__ hlnbL,
                float* __restrict__ hln, float* __restrict__ inner,
                const __hip_bfloat16* __restrict__ xpwH, const __hip_bfloat16* __restrict__ xpwL,
                const float* __restrict__ fw_bias, const float* __restrict__ bw_bias,
                const float* __restrict__ fw_ln0g, const float* __restrict__ fw_ln0b,
                const float* __restrict__ fw_ln3g, const float* __restrict__ fw_ln3b,
                const float* __restrict__ bw_ln0g, const float* __restrict__ bw_ln0b,
                const float* __restrict__ bw_ln3g, const float* __restrict__ bw_ln3b,
                float* __restrict__ out_tv,
                int dG, int doG, int dU, int tU, int doU) {
  __shared__ __align__(16) __hip_bfloat16 As[2][4096];   // [plane][64x64]
  __shared__ __align__(16) __hip_bfloat16 Bs[2][4096];
  __shared__ float red[8];

  const int bid = blockIdx.x;
  const int tid = threadIdx.x;

  if (bid < GBLK) {
    // ================= GEMM part =================
    if (!doG) return;
    const int x  = bid & 7;            // ~xcd
    const int kp = x >> 1;             // 0..3 K-quarter
    const int nh = x & 1;              // nt half
    const int i  = bid >> 3;           // 0..57
    const int m  = i & 1;
    const int nt = (i >> 1) + 29 * nh; // 0..57
    const int ks0 = kp * 5;
    const int ks1 = (kp == 3) ? 19 : (ks0 + 5);
    const int m0 = m * 64;
    const int n0 = nt * 64;

    const int lane = tid & 63;
    const int wid = tid >> 6;
    const int wr = wid >> 1, wc = wid & 1;

    const __hip_bfloat16* WH = rkTH + (size_t)dG * NP * KU;
    const __hip_bfloat16* WL = rkTL + (size_t)dG * NP * KU;

    f32x4 acc[2][2] = {};
    const int srow = tid >> 3;
    const int scol = swz_scol(tid);

    for (int ks = ks0; ks < ks1; ++ks) {
      const int k0 = ks * 64;
      __syncthreads();
#pragma unroll
      for (int it = 0; it < 2; ++it) {
        const size_t ga = (size_t)(dG * B_ + m0 + it * 32 + srow) * KU + k0 + scol;
        lds_load16(hlnbH + ga, &As[0][it * 2048 + tid * 8]);
        lds_load16(hlnbL + ga, &As[1][it * 2048 + tid * 8]);
        const size_t gb = (size_t)(n0 + it * 32 + srow) * KU + k0 + scol;
        lds_load16(WH + gb, &Bs[0][it * 2048 + tid * 8]);
        lds_load16(WL + gb, &Bs[1][it * 2048 + tid * 8]);
      }
      __syncthreads();
#pragma unroll
      for (int kk = 0; kk < 2; ++kk) {
        short8 ah[2], al[2], bh[2], bl[2];
#pragma unroll
        for (int mi = 0; mi < 2; ++mi) {
          const int row = wr * 32 + mi * 16 + (lane & 15);
          const int off = swz_off(row, kk, lane);
          ah[mi] = *(const short8*)(&As[0][off]);
          al[mi] = *(const short8*)(&As[1][off]);
        }
#pragma unroll
        for (int nf = 0; nf < 2; ++nf) {
          const int row = wc * 32 + nf * 16 + (lane & 15);
          const int off = swz_off(row, kk, lane);
          bh[nf] = *(const short8*)(&Bs[0][off]);
          bl[nf] = *(const short8*)(&Bs[1][off]);
        }
#pragma unroll
        for (int mi = 0; mi < 2; ++mi)
#pragma unroll
          for (int nf = 0; nf < 2; ++nf) {
            acc[mi][nf] = __builtin_amdgcn_mfma_f32_16x16x32_bf16(ah[mi], bh[nf], acc[mi][nf], 0, 0, 0);
            acc[mi][nf] = __builtin_amdgcn_mfma_f32_16x16x32_bf16(ah[mi], bl[nf], acc[mi][nf], 0, 0, 0);
            acc[mi][nf] = __builtin_amdgcn_mfma_f32_16x16x32_bf16(al[mi], bh[nf], acc[mi][nf], 0, 0, 0);
          }
      }
    }

    float* C = inner + (size_t)(dG * 4 + kp) * B_ * NP;
#pragma unroll
    for (int mi = 0; mi < 2; ++mi)
#pragma unroll
      for (int nf = 0; nf < 2; ++nf) {
        const int gc = n0 + wc * 32 + nf * 16 + (lane & 15);
        const int gr = m0 + wr * 32 + mi * 16 + ((lane >> 4) << 2);
#pragma unroll
        for (int j = 0; j < 4; ++j)
          C[(size_t)(gr + j) * NP + gc] = acc[mi][nf][j];
      }
    return;
  }

  // ================= UPDATE part =================
  if (!doU) return;
  const int r = bid - GBLK;            // 0..127
  const int d = dU;
  const int srel = tU & (WIN - 1);

  const float* rec0 = inner + ((size_t)(d * 4 + 0) * B_ + r) * NP;
  const float* rec1 = inner + ((size_t)(d * 4 + 1) * B_ + r) * NP;
  const float* rec2 = inner + ((size_t)(d * 4 + 2) * B_ + r) * NP;
  const float* rec3 = inner + ((size_t)(d * 4 + 3) * B_ + r) * NP;
  const size_t xoff = ((size_t)(d * WIN + srel) * B_ + r) * NP;
  const __hip_bfloat16* xH = xpwH + xoff;
  const __hip_bfloat16* xL = xpwL + xoff;
  const float* rb = (d ? bw_bias : fw_bias) + N3;
  const float* g0 = d ? bw_ln0g : fw_ln0g;
  const float* b0 = d ? bw_ln0b : fw_ln0b;
  const float* g3 = d ? bw_ln3g : fw_ln3g;
  const float* b3 = d ? bw_ln3b : fw_ln3b;
  float* hl = hln + ((size_t)d * B_ + r) * U_;
  __hip_bfloat16* hlbH = hlnbH + ((size_t)d * B_ + r) * KU;
  __hip_bfloat16* hlbL = hlnbL + ((size_t)d * B_ + r) * KU;

  float zv[5], cv[5], hv[5];
  float s1 = 0.f, s2 = 0.f;
#pragma unroll
  for (int i = 0; i < 5; ++i) {
    const int c = tid + i * 256;
    if (c < U_) {
      const float xz = __bfloat162float(xH[c]) + __bfloat162float(xL[c]);
      const float xg = __bfloat162float(xH[U_ + c]) + __bfloat162float(xL[U_ + c]);
      const float xh = __bfloat162float(xH[2 * U_ + c]) + __bfloat162float(xL[2 * U_ + c]);
      const float rz = (rec0[c] + rec1[c]) + (rec2[c] + rec3[c]);
      const float rg = (rec0[U_ + c] + rec1[U_ + c]) + (rec2[U_ + c] + rec3[U_ + c]);
      const float rh = (rec0[2 * U_ + c] + rec1[2 * U_ + c]) + (rec2[2 * U_ + c] + rec3[2 * U_ + c]);
      const float z  = sigmf(xz + rz + rb[c]);
      const float rr = sigmf(xg + rg + rb[U_ + c]);
      const float cand = xh + rr * (rh + rb[2 * U_ + c]);
      zv[i] = z; cv[i] = cand;
      s1 += cand; s2 += cand * cand;
    }
  }
  breduce2(s1, s2, red, tid);
  const float m1 = s1 / U_;
  const float is1 = rsqrtf(s2 / U_ - m1 * m1 + LN_EPS);

  float t1 = 0.f, t2 = 0.f;
#pragma unroll
  for (int i = 0; i < 5; ++i) {
    const int c = tid + i * 256;
    if (c < U_) {
      const float hh = tanhf(g3[c] * (cv[i] - m1) * is1 + b3[c]);
      const float hn = zv[i] * hl[c] + (1.f - zv[i]) * hh;
      hv[i] = hn;
      t1 += hn; t2 += hn * hn;
    }
  }
  breduce2(t1, t2, red, tid);
  const float m2 = t1 / U_;
  const float is2 = rsqrtf(t2 / U_ - m2 * m2 + LN_EPS);

#pragma unroll
  for (int i = 0; i < 5; ++i) {
    const int c = tid + i * 256;
    if (c < U_) {
      const float hlnew = g0[c] * (hv[i] - m2) * is2 + b0[c];
      hl[c] = hlnew;
      const __hip_bfloat16 hi = __float2bfloat16(hlnew);
      hlbH[c] = hi;
      hlbL[c] = __float2bfloat16(hlnew - __bfloat162float(hi));
      if (tU == T_ - 1) out_tv[(size_t)r * 2400 + (size_t)d * U_ + c] = hv[i];
    }
  }
}

// ---------------- host-side launch ----------------
extern "C" void kernel_launch(void* const* d_in, const int* in_sizes, int n_in,
                              void* d_out, int out_size, void* d_ws, size_t ws_size,
                              hipStream_t stream) {
  const int*   sent      = (const int*)  d_in[0];
  const float* embed     = (const float*)d_in[1];
  const float* fw_kernel = (const float*)d_in[2];
  const float* fw_rkern  = (const float*)d_in[3];
  const float* fw_bias   = (const float*)d_in[4];
  const float* fw_ln0g   = (const float*)d_in[5];
  const float* fw_ln0b   = (const float*)d_in[6];
  const float* fw_ln3g   = (const float*)d_in[7];
  const float* fw_ln3b   = (const float*)d_in[8];
  const float* bw_kernel = (const float*)d_in[9];
  const float* bw_rkern  = (const float*)d_in[10];
  const float* bw_bias   = (const float*)d_in[11];
  const float* bw_ln0g   = (const float*)d_in[12];
  const float* bw_ln0b   = (const float*)d_in[13];
  const float* bw_ln3g   = (const float*)d_in[14];
  const float* bw_ln3b   = (const float*)d_in[15];

  uint8_t* ws = (uint8_t*)d_ws;
  __hip_bfloat16* embH  = (__hip_bfloat16*)(ws + OFF_EMBH);
  __hip_bfloat16* embL  = (__hip_bfloat16*)(ws + OFF_EMBL);
  __hip_bfloat16* kTH   = (__hip_bfloat16*)(ws + OFF_KTH);
  __hip_bfloat16* kTL   = (__hip_bfloat16*)(ws + OFF_KTL);
  __hip_bfloat16* rkTH  = (__hip_bfloat16*)(ws + OFF_RKTH);
  __hip_bfloat16* rkTL  = (__hip_bfloat16*)(ws + OFF_RKTL);
  __hip_bfloat16* xpwH  = (__hip_bfloat16*)(ws + OFF_XPWH);
  __hip_bfloat16* xpwL  = (__hip_bfloat16*)(ws + OFF_XPWL);
  float*          inner = (float*)(ws + OFF_INNER);
  float*          hln   = (float*)(ws + OFF_HLN);
  __hip_bfloat16* hlnbH = (__hip_bfloat16*)(ws + OFF_HLNBH);
  __hip_bfloat16* hlnbL = (__hip_bfloat16*)(ws + OFF_HLNBL);

  float* out_tv  = (float*)d_out;                        // [128][2400]
  float* out_emb = (float*)d_out + (size_t)B_ * 2 * U_;  // [8192][620]

  // K1: embedding gather + tanh (fp32 + hi/lo bf16 planes)
  embed_kernel<<<B_ * T_, 256, 0, stream>>>(sent, embed, out_emb, embH, embL);

  // K2: weight transpose+cast hi/lo (both dirs each)
  transpose_cast<<<dim3(NP / 32, KE / 32, 2), dim3(32, 8), 0, stream>>>(
      fw_kernel, bw_kernel, kTH, kTL, E_, KE);
  transpose_cast<<<dim3(NP / 32, KU / 32, 2), dim3(32, 8), 0, stream>>>(
      fw_rkern, bw_rkern, rkTH, rkTL, U_, KU);

  // K4: h_ln = LN(0) = beta
  init_hln<<<(2 * B_ * KU + 255) / 256, 256, 0, stream>>>(fw_ln0b, bw_ln0b,
                                                          hln, hlnbH, hlnbL);

#define SF(dG_, doG_, dU_, tU_, doU_)                                          \
  step_fused<<<TBLK, 256, 0, stream>>>(                                        \
      rkTH, rkTL, hlnbH, hlnbL, hln, inner, xpwH, xpwL,                        \
      fw_bias, bw_bias, fw_ln0g, fw_ln0b, fw_ln3g, fw_ln3b,                    \
      bw_ln0g, bw_ln0b, bw_ln3g, bw_ln3b, out_tv,                              \
      dG_, doG_, dU_, tU_, doU_)

  // staggered scan: A_t = {G d0@t || U d1@(t-1)}, [xwin at window starts],
  //                 B_t = {G d1@t || U d0@t}
  for (int t = 0; t < T_; ++t) {
    SF(0, 1, 1, t - 1, (t > 0) ? 1 : 0);
    if ((t & (WIN - 1)) == 0)
      xwin_gemm<<<928, 256, 0, stream>>>(
          embH, embL, kTH, kTL, fw_bias, bw_bias, xpwH, xpwL, t);
    SF(1, 1, 0, t, 1);
  }
  SF(0, 0, 1, T_ - 1, 1);   // final update for d1@63
#undef SF
}

// Round 8
// 1824.756 us; speedup vs baseline: 5.2031x; 1.1133x over previous
//
#include <hip/hip_runtime.h>
#include <hip/hip_bf16.h>

// Sizes
#define U_    1200
#define E_    620
#define B_    128
#define T_    64
#define N3    3600           // 3*U
#define NP    3712           // padded 3U = 29*128
#define KE    640            // padded E  = 10*64
#define KU    1216           // padded U  = 19*64
#define WIN   16             // xproj window (scan steps per window GEMM)
#define LN_EPS 1e-3f

#define GBLK  232            // GEMM blocks per launch (8 xcd * 29)
#define UBLK  128            // update blocks per launch
#define TBLK  (GBLK + UBLK)  // 360

typedef __attribute__((ext_vector_type(8))) short short8;
typedef __attribute__((ext_vector_type(4))) float f32x4;
typedef _Float16 f16;
typedef __attribute__((ext_vector_type(8))) _Float16 half8;

// ---------------- workspace layout (bytes) ----------------
constexpr size_t OFF_EMBH  = 0;                                   // bf16 [8192][KE] hi
constexpr size_t SZ_EMB    = (size_t)8192 * KE * 2;
constexpr size_t OFF_EMBL  = OFF_EMBH + SZ_EMB;
constexpr size_t OFF_KTH   = OFF_EMBL + SZ_EMB;                   // bf16 [2][NP][KE] hi
constexpr size_t SZ_KT     = (size_t)2 * NP * KE * 2;
constexpr size_t OFF_KTL   = OFF_KTH + SZ_KT;
constexpr size_t OFF_RKF   = OFF_KTL + SZ_KT;                     // f16 [2][NP][KU]
constexpr size_t SZ_RKF    = (size_t)2 * NP * KU * 2;
constexpr size_t OFF_XPWH  = OFF_RKF + SZ_RKF;                    // bf16 [2][WIN][B][NP] hi
constexpr size_t SZ_XPW    = (size_t)2 * WIN * B_ * NP * 2;
constexpr size_t OFF_XPWL  = OFF_XPWH + SZ_XPW;
constexpr size_t OFF_INNER = OFF_XPWL + SZ_XPW;                   // f32 [2d*2kp][B][NP]
constexpr size_t SZ_INNER  = (size_t)4 * B_ * NP * 4;
constexpr size_t OFF_HLN   = OFF_INNER + SZ_INNER;                // f32 [2][B][U]
constexpr size_t SZ_HLN    = (size_t)2 * B_ * U_ * 4;
constexpr size_t OFF_HLFH  = OFF_HLN + SZ_HLN;                    // f16 [2][B][KU] hi
constexpr size_t SZ_HLF    = (size_t)2 * B_ * KU * 2;
constexpr size_t OFF_HLFL  = OFF_HLFH + SZ_HLF;

__device__ inline void lds_load16(const void* g, void* l) {
  __builtin_amdgcn_global_load_lds(
      (const __attribute__((address_space(1))) unsigned int*)g,
      (__attribute__((address_space(3))) unsigned int*)l, 16, 0, 0);
}

__device__ inline float sigmf(float x) { return 1.f / (1.f + expf(-x)); }

// Swizzle helpers (verified r6/r7: 0 bank conflicts). LDS tiles [rows][64 elems
// of 2B]; stage pre-swizzles the GLOBAL column group, read XORs in-row offset.
__device__ inline int swz_scol(int tid) {
  return (((tid & 7) ^ ((tid >> 3) & 7)) << 3);
}
__device__ inline int swz_off(int row, int kk, int lane) {
  return row * 64 + ((kk * 32 + ((lane >> 4) << 3)) ^ ((row & 7) << 3));
}

// ---------------- K1: embedding gather + tanh (fp32 out + hi/lo bf16) -----
__global__ __launch_bounds__(256)
void embed_kernel(const int* __restrict__ sent, const float* __restrict__ embed,
                  float* __restrict__ out_emb,
                  __hip_bfloat16* __restrict__ embH, __hip_bfloat16* __restrict__ embL) {
  const int row = blockIdx.x;                 // b*T + t
  const int idx = sent[row];
  const float* src = embed + (size_t)idx * E_;
  for (int e = threadIdx.x; e < KE; e += 256) {
    float v = 0.f;
    if (e < E_) {
      v = tanhf(src[e]);
      out_emb[(size_t)row * E_ + e] = v;
    }
    const __hip_bfloat16 hi = __float2bfloat16(v);
    embH[(size_t)row * KE + e] = hi;
    embL[(size_t)row * KE + e] = __float2bfloat16(v - __bfloat162float(hi));
  }
}

// ---------------- K2a: transpose+cast [K][3600]f32 -> [NP][Kp] hi/lo bf16 --
__global__ __launch_bounds__(256)
void transpose_cast(const float* __restrict__ W0, const float* __restrict__ W1,
                    __hip_bfloat16* __restrict__ WtHi, __hip_bfloat16* __restrict__ WtLo,
                    int Kreal, int Kp) {
  const int d = blockIdx.z;
  const float* W = d ? W1 : W0;
  __hip_bfloat16* dstH = WtHi + (size_t)d * NP * Kp;
  __hip_bfloat16* dstL = WtLo + (size_t)d * NP * Kp;
  __shared__ float tile[32][33];
  const int n0 = blockIdx.x * 32, k0 = blockIdx.y * 32;
  const int tx = threadIdx.x, ty = threadIdx.y;   // 32 x 8
#pragma unroll
  for (int i = 0; i < 32; i += 8) {
    const int k = k0 + ty + i, n = n0 + tx;
    tile[ty + i][tx] = (k < Kreal && n < N3) ? W[(size_t)k * N3 + n] : 0.f;
  }
  __syncthreads();
#pragma unroll
  for (int i = 0; i < 32; i += 8) {
    const int n = n0 + ty + i, k = k0 + tx;
    const float v = tile[tx][ty + i];
    const __hip_bfloat16 hi = __float2bfloat16(v);
    dstH[(size_t)n * Kp + k] = hi;
    dstL[(size_t)n * Kp + k] = __float2bfloat16(v - __bfloat162float(hi));
  }
}

// ---------------- K2b: transpose+cast [K][3600]f32 -> [NP][Kp] f16 --------
__global__ __launch_bounds__(256)
void transpose_cast_f16(const float* __restrict__ W0, const float* __restrict__ W1,
                        f16* __restrict__ Wt, int Kreal, int Kp) {
  const int d = blockIdx.z;
  const float* W = d ? W1 : W0;
  f16* dst = Wt + (size_t)d * NP * Kp;
  __shared__ float tile[32][33];
  const int n0 = blockIdx.x * 32, k0 = blockIdx.y * 32;
  const int tx = threadIdx.x, ty = threadIdx.y;   // 32 x 8
#pragma unroll
  for (int i = 0; i < 32; i += 8) {
    const int k = k0 + ty + i, n = n0 + tx;
    tile[ty + i][tx] = (k < Kreal && n < N3) ? W[(size_t)k * N3 + n] : 0.f;
  }
  __syncthreads();
#pragma unroll
  for (int i = 0; i < 32; i += 8) {
    const int n = n0 + ty + i, k = k0 + tx;
    dst[(size_t)n * Kp + k] = (f16)tile[tx][ty + i];
  }
}

// ---------------- K4: init h_ln = LN(0) = beta ----------------
__global__ __launch_bounds__(256)
void init_hln(const float* __restrict__ fw_b0, const float* __restrict__ bw_b0,
              float* __restrict__ hln, f16* __restrict__ hlfH, f16* __restrict__ hlfL) {
  const int idx = blockIdx.x * 256 + threadIdx.x;   // [2*128*KU]
  if (idx >= 2 * B_ * KU) return;
  const int k = idx % KU;
  const int rowd = idx / KU;
  const int d = rowd >> 7;
  float v = 0.f;
  if (k < U_) {
    v = (d ? bw_b0 : fw_b0)[k];
    hln[(size_t)rowd * U_ + k] = v;
  }
  const f16 hi = (f16)v;
  hlfH[idx] = hi;
  hlfL[idx] = (f16)(v - (float)hi);
}

// ---------------- window GEMM: x+ib for WIN scan steps, hi/lo out ---------
// (unchanged from r6/r7: bf16 hi/lo 3-term, swizzled, 0 conflicts)
__global__ __launch_bounds__(256)
void xwin_gemm(const __hip_bfloat16* __restrict__ embH, const __hip_bfloat16* __restrict__ embL,
               const __hip_bfloat16* __restrict__ kTH, const __hip_bfloat16* __restrict__ kTL,
               const float* __restrict__ fw_bias, const float* __restrict__ bw_bias,
               __hip_bfloat16* __restrict__ xpwH, __hip_bfloat16* __restrict__ xpwL,
               int w0) {
  constexpr int BM = 128, BN = 128, BK = 64;
  constexpr int WM = 64, WN = 64, FM = 4, FN = 4;
  constexpr int TA = BM * BK, TB = BN * BK;       // 8192 elems
  const int bid = blockIdx.x;
  const int w = (bid & 7) * 116 + (bid >> 3);     // bijective: 928 = 8*116
  const int d = w / 464;
  const int q = w % 464;
  const int nt = q / 16, mt = q % 16;
  const int m0 = mt * BM;
  const int n0 = nt * BN;

  const __hip_bfloat16* BH = kTH + (size_t)d * NP * KE;
  const __hip_bfloat16* BL = kTL + (size_t)d * NP * KE;

  const int tid = threadIdx.x;
  const int lane = tid & 63;
  const int wid = tid >> 6;
  const int wr = wid >> 1, wc = wid & 1;

  __shared__ __align__(16) __hip_bfloat16 As[2 * TA];
  __shared__ __align__(16) __hip_bfloat16 Bs[2 * TB];

  f32x4 acc[FM][FN] = {};

  const int srow = tid >> 3;
  const int scol = swz_scol(tid);

  for (int ks = 0; ks < KE / BK; ++ks) {
    const int k0 = ks * BK;
    __syncthreads();
#pragma unroll
    for (int it = 0; it < TA / 2048; ++it) {
      const int row = m0 + it * 32 + srow;       // m index
      const int b = row & 127, srel = row >> 7;
      const int txi = d ? (T_ - 1 - (w0 + srel)) : (w0 + srel);
      const size_t goff = (size_t)(b * T_ + txi) * KE + k0 + scol;
      lds_load16(embH + goff, As + it * 2048 + tid * 8);
      lds_load16(embL + goff, As + TA + it * 2048 + tid * 8);
    }
#pragma unroll
    for (int it = 0; it < TB / 2048; ++it) {
      const size_t goff = (size_t)(n0 + it * 32 + srow) * KE + k0 + scol;
      lds_load16(BH + goff, Bs + it * 2048 + tid * 8);
      lds_load16(BL + goff, Bs + TB + it * 2048 + tid * 8);
    }
    __syncthreads();
#pragma unroll
    for (int kk = 0; kk < BK / 32; ++kk) {
      short8 ah[FM], al[FM], bh[FN], bl[FN];
#pragma unroll
      for (int mi = 0; mi < FM; ++mi) {
        const int row = wr * WM + mi * 16 + (lane & 15);
        const int off = swz_off(row, kk, lane);
        ah[mi] = *(const short8*)(As + off);
        al[mi] = *(const short8*)(As + TA + off);
      }
#pragma unroll
      for (int ni = 0; ni < FN; ++ni) {
        const int row = wc * WN + ni * 16 + (lane & 15);
        const int off = swz_off(row, kk, lane);
        bh[ni] = *(const short8*)(Bs + off);
        bl[ni] = *(const short8*)(Bs + TB + off);
      }
#pragma unroll
      for (int mi = 0; mi < FM; ++mi)
#pragma unroll
        for (int ni = 0; ni < FN; ++ni) {
          acc[mi][ni] = __builtin_amdgcn_mfma_f32_16x16x32_bf16(ah[mi], bh[ni], acc[mi][ni], 0, 0, 0);
          acc[mi][ni] = __builtin_amdgcn_mfma_f32_16x16x32_bf16(ah[mi], bl[ni], acc[mi][ni], 0, 0, 0);
          acc[mi][ni] = __builtin_amdgcn_mfma_f32_16x16x32_bf16(al[mi], bh[ni], acc[mi][ni], 0, 0, 0);
        }
    }
  }

  const float* ib = d ? bw_bias : fw_bias;
#pragma unroll
  for (int mi = 0; mi < FM; ++mi)
#pragma unroll
    for (int ni = 0; ni < FN; ++ni) {
      const int gc = n0 + wc * WN + ni * 16 + (lane & 15);
      const float bv = (gc < N3) ? ib[gc] : 0.f;
      const int gr0 = m0 + wr * WM + mi * 16 + ((lane >> 4) << 2);
#pragma unroll
      for (int j = 0; j < 4; ++j) {
        const int gr = gr0 + j;
        const int b = gr & 127, srel = gr >> 7;
        const size_t off = ((size_t)(d * WIN + srel) * B_ + b) * NP + gc;
        const float v = acc[mi][ni][j] + bv;
        const __hip_bfloat16 hi = __float2bfloat16(v);
        xpwH[off] = hi;
        xpwL[off] = __float2bfloat16(v - __bfloat162float(hi));
      }
    }
}

// ---------------- block-wide 2-value sum reduction ----------------
__device__ inline void breduce2(float& a, float& b, float* red, int tid) {
#pragma unroll
  for (int off = 32; off; off >>= 1) {
    a += __shfl_down(a, off, 64);
    b += __shfl_down(b, off, 64);
  }
  const int w = tid >> 6;
  __syncthreads();
  if ((tid & 63) == 0) { red[w] = a; red[4 + w] = b; }
  __syncthreads();
  a = red[0] + red[1] + red[2] + red[3];
  b = red[4] + red[5] + red[6] + red[7];
}

// ---------------- fused scan step: GEMM(dG,t) || UPDATE(dU,tU) ------------
// GEMM blocks [0,232): rec = h_ln @ rkernel^T, A = f16 hi/lo (2-term), W =
// single f16 (L2-resident: both dirs = 18 MB <= 32 MB aggregate L2; XCD
// decode pins a 2.26 MB (kp,nh) slab per XCD per dir). split-K2 ->
// inner[2d*2kp] f32 partials. Update blocks [232,360): other direction.
__global__ __launch_bounds__(256)
void step_fused(const f16* __restrict__ rkF,
                f16* __restrict__ hlfH, f16* __restrict__ hlfL,
                float* __restrict__ hln, float* __restrict__ inner,
                const __hip_bfloat16* __restrict__ xpwH, const __hip_bfloat16* __restrict__ xpwL,
                const float* __restrict__ fw_bias, const float* __restrict__ bw_bias,
                const float* __restrict__ fw_ln0g, const float* __restrict__ fw_ln0b,
                const float* __restrict__ fw_ln3g, const float* __restrict__ fw_ln3b,
                const float* __restrict__ bw_ln0g, const float* __restrict__ bw_ln0b,
                const float* __restrict__ bw_ln3g, const float* __restrict__ bw_ln3b,
                float* __restrict__ out_tv,
                int dG, int doG, int dU, int tU, int doU) {
  __shared__ __align__(16) f16 As[2][4096];   // [plane][64x64]
  __shared__ __align__(16) f16 Bs[4096];
  __shared__ float red[8];

  const int bid = blockIdx.x;
  const int tid = threadIdx.x;

  if (bid < GBLK) {
    // ================= GEMM part =================
    if (!doG) return;
    const int x  = bid & 7;            // ~xcd: (kp, nh, m)
    const int kp = x >> 2;             // K half
    const int nh = (x >> 1) & 1;       // nt half
    const int m  = x & 1;
    const int i  = bid >> 3;           // 0..28
    const int nt = i + 29 * nh;        // 0..57
    const int ks0 = kp ? 10 : 0;
    const int ks1 = kp ? 19 : 10;
    const int m0 = m * 64;
    const int n0 = nt * 64;

    const int lane = tid & 63;
    const int wid = tid >> 6;
    const int wr = wid >> 1, wc = wid & 1;

    const f16* WF = rkF + (size_t)dG * NP * KU;

    f32x4 acc[2][2] = {};
    const int srow = tid >> 3;
    const int scol = swz_scol(tid);

    for (int ks = ks0; ks < ks1; ++ks) {
      const int k0 = ks * 64;
      __syncthreads();
#pragma unroll
      for (int it = 0; it < 2; ++it) {
        const size_t ga = (size_t)(dG * B_ + m0 + it * 32 + srow) * KU + k0 + scol;
        lds_load16(hlfH + ga, &As[0][it * 2048 + tid * 8]);
        lds_load16(hlfL + ga, &As[1][it * 2048 + tid * 8]);
        const size_t gb = (size_t)(n0 + it * 32 + srow) * KU + k0 + scol;
        lds_load16(WF + gb, &Bs[it * 2048 + tid * 8]);
      }
      __syncthreads();
#pragma unroll
      for (int kk = 0; kk < 2; ++kk) {
        half8 ah[2], al[2], bv[2];
#pragma unroll
        for (int mi = 0; mi < 2; ++mi) {
          const int row = wr * 32 + mi * 16 + (lane & 15);
          const int off = swz_off(row, kk, lane);
          ah[mi] = *(const half8*)(&As[0][off]);
          al[mi] = *(const half8*)(&As[1][off]);
        }
#pragma unroll
        for (int nf = 0; nf < 2; ++nf) {
          const int row = wc * 32 + nf * 16 + (lane & 15);
          const int off = swz_off(row, kk, lane);
          bv[nf] = *(const half8*)(&Bs[off]);
        }
#pragma unroll
        for (int mi = 0; mi < 2; ++mi)
#pragma unroll
          for (int nf = 0; nf < 2; ++nf) {
            acc[mi][nf] = __builtin_amdgcn_mfma_f32_16x16x32_f16(ah[mi], bv[nf], acc[mi][nf], 0, 0, 0);
            acc[mi][nf] = __builtin_amdgcn_mfma_f32_16x16x32_f16(al[mi], bv[nf], acc[mi][nf], 0, 0, 0);
          }
      }
    }

    float* C = inner + (size_t)(dG * 2 + kp) * B_ * NP;
#pragma unroll
    for (int mi = 0; mi < 2; ++mi)
#pragma unroll
      for (int nf = 0; nf < 2; ++nf) {
        const int gc = n0 + wc * 32 + nf * 16 + (lane & 15);
        const int gr = m0 + wr * 32 + mi * 16 + ((lane >> 4) << 2);
#pragma unroll
        for (int j = 0; j < 4; ++j)
          C[(size_t)(gr + j) * NP + gc] = acc[mi][nf][j];
      }
    return;
  }

  // ================= UPDATE part =================
  if (!doU) return;
  const int r = bid - GBLK;            // 0..127
  const int d = dU;
  const int srel = tU & (WIN - 1);

  const float* rec0 = inner + ((size_t)(d * 2 + 0) * B_ + r) * NP;
  const float* rec1 = inner + ((size_t)(d * 2 + 1) * B_ + r) * NP;
  const size_t xoff = ((size_t)(d * WIN + srel) * B_ + r) * NP;
  const __hip_bfloat16* xH = xpwH + xoff;
  const __hip_bfloat16* xL = xpwL + xoff;
  const float* rb = (d ? bw_bias : fw_bias) + N3;
  const float* g0 = d ? bw_ln0g : fw_ln0g;
  const float* b0 = d ? bw_ln0b : fw_ln0b;
  const float* g3 = d ? bw_ln3g : fw_ln3g;
  const float* b3 = d ? bw_ln3b : fw_ln3b;
  float* hl = hln + ((size_t)d * B_ + r) * U_;
  f16* hlbH = hlfH + ((size_t)d * B_ + r) * KU;
  f16* hlbL = hlfL + ((size_t)d * B_ + r) * KU;

  float zv[5], cv[5], hv[5];
  float s1 = 0.f, s2 = 0.f;
#pragma unroll
  for (int i = 0; i < 5; ++i) {
    const int c = tid + i * 256;
    if (c < U_) {
      const float xz = __bfloat162float(xH[c]) + __bfloat162float(xL[c]);
      const float xg = __bfloat162float(xH[U_ + c]) + __bfloat162float(xL[U_ + c]);
      const float xh = __bfloat162float(xH[2 * U_ + c]) + __bfloat162float(xL[2 * U_ + c]);
      const float rz = rec0[c] + rec1[c];
      const float rg = rec0[U_ + c] + rec1[U_ + c];
      const float rh = rec0[2 * U_ + c] + rec1[2 * U_ + c];
      const float z  = sigmf(xz + rz + rb[c]);
      const float rr = sigmf(xg + rg + rb[U_ + c]);
      const float cand = xh + rr * (rh + rb[2 * U_ + c]);
      zv[i] = z; cv[i] = cand;
      s1 += cand; s2 += cand * cand;
    }
  }
  breduce2(s1, s2, red, tid);
  const float m1 = s1 / U_;
  const float is1 = rsqrtf(s2 / U_ - m1 * m1 + LN_EPS);

  float t1 = 0.f, t2 = 0.f;
#pragma unroll
  for (int i = 0; i < 5; ++i) {
    const int c = tid + i * 256;
    if (c < U_) {
      const float hh = tanhf(g3[c] * (cv[i] - m1) * is1 + b3[c]);
      const float hn = zv[i] * hl[c] + (1.f - zv[i]) * hh;
      hv[i] = hn;
      t1 += hn; t2 += hn * hn;
    }
  }
  breduce2(t1, t2, red, tid);
  const float m2 = t1 / U_;
  const float is2 = rsqrtf(t2 / U_ - m2 * m2 + LN_EPS);

#pragma unroll
  for (int i = 0; i < 5; ++i) {
    const int c = tid + i * 256;
    if (c < U_) {
      const float hlnew = g0[c] * (hv[i] - m2) * is2 + b0[c];
      hl[c] = hlnew;
      const f16 hi = (f16)hlnew;
      hlbH[c] = hi;
      hlbL[c] = (f16)(hlnew - (float)hi);
      if (tU == T_ - 1) out_tv[(size_t)r * 2400 + (size_t)d * U_ + c] = hv[i];
    }
  }
}

// ---------------- host-side launch ----------------
extern "C" void kernel_launch(void* const* d_in, const int* in_sizes, int n_in,
                              void* d_out, int out_size, void* d_ws, size_t ws_size,
                              hipStream_t stream) {
  const int*   sent      = (const int*)  d_in[0];
  const float* embed     = (const float*)d_in[1];
  const float* fw_kernel = (const float*)d_in[2];
  const float* fw_rkern  = (const float*)d_in[3];
  const float* fw_bias   = (const float*)d_in[4];
  const float* fw_ln0g   = (const float*)d_in[5];
  const float* fw_ln0b   = (const float*)d_in[6];
  const float* fw_ln3g   = (const float*)d_in[7];
  const float* fw_ln3b   = (const float*)d_in[8];
  const float* bw_kernel = (const float*)d_in[9];
  const float* bw_rkern  = (const float*)d_in[10];
  const float* bw_bias   = (const float*)d_in[11];
  const float* bw_ln0g   = (const float*)d_in[12];
  const float* bw_ln0b   = (const float*)d_in[13];
  const float* bw_ln3g   = (const float*)d_in[14];
  const float* bw_ln3b   = (const float*)d_in[15];

  uint8_t* ws = (uint8_t*)d_ws;
  __hip_bfloat16* embH  = (__hip_bfloat16*)(ws + OFF_EMBH);
  __hip_bfloat16* embL  = (__hip_bfloat16*)(ws + OFF_EMBL);
  __hip_bfloat16* kTH   = (__hip_bfloat16*)(ws + OFF_KTH);
  __hip_bfloat16* kTL   = (__hip_bfloat16*)(ws + OFF_KTL);
  f16*            rkF   = (f16*)(ws + OFF_RKF);
  __hip_bfloat16* xpwH  = (__hip_bfloat16*)(ws + OFF_XPWH);
  __hip_bfloat16* xpwL  = (__hip_bfloat16*)(ws + OFF_XPWL);
  float*          inner = (float*)(ws + OFF_INNER);
  float*          hln   = (float*)(ws + OFF_HLN);
  f16*            hlfH  = (f16*)(ws + OFF_HLFH);
  f16*            hlfL  = (f16*)(ws + OFF_HLFL);

  float* out_tv  = (float*)d_out;                        // [128][2400]
  float* out_emb = (float*)d_out + (size_t)B_ * 2 * U_;  // [8192][620]

  // K1: embedding gather + tanh (fp32 + hi/lo bf16 planes)
  embed_kernel<<<B_ * T_, 256, 0, stream>>>(sent, embed, out_emb, embH, embL);

  // K2: weight transpose+cast — kernel: bf16 hi/lo; rkernel: single f16
  transpose_cast<<<dim3(NP / 32, KE / 32, 2), dim3(32, 8), 0, stream>>>(
      fw_kernel, bw_kernel, kTH, kTL, E_, KE);
  transpose_cast_f16<<<dim3(NP / 32, KU / 32, 2), dim3(32, 8), 0, stream>>>(
      fw_rkern, bw_rkern, rkF, U_, KU);

  // K4: h_ln = LN(0) = beta
  init_hln<<<(2 * B_ * KU + 255) / 256, 256, 0, stream>>>(fw_ln0b, bw_ln0b,
                                                          hln, hlfH, hlfL);

#define SF(dG_, doG_, dU_, tU_, doU_)                                          \
  step_fused<<<TBLK, 256, 0, stream>>>(                                        \
      rkF, hlfH, hlfL, hln, inner, xpwH, xpwL,                                 \
      fw_bias, bw_bias, fw_ln0g, fw_ln0b, fw_ln3g, fw_ln3b,                    \
      bw_ln0g, bw_ln0b, bw_ln3g, bw_ln3b, out_tv,                              \
      dG_, doG_, dU_, tU_, doU_)

  // staggered scan: A_t = {G d0@t || U d1@(t-1)}, [xwin at window starts],
  //                 B_t = {G d1@t || U d0@t}
  for (int t = 0; t < T_; ++t) {
    SF(0, 1, 1, t - 1, (t > 0) ? 1 : 0);
    if ((t & (WIN - 1)) == 0)
      xwin_gemm<<<928, 256, 0, stream>>>(
          embH, embL, kTH, kTL, fw_bias, bw_bias, xpwH, xpwL, t);
    SF(1, 1, 0, t, 1);
  }
  SF(0, 0, 1, T_ - 1, 1);   // final update for d1@63
#undef SF
}